// Round 9
// baseline (1024.775 us; speedup 1.0000x reference)
//
#include <hip/hip_runtime.h>
#include <hip/hip_bf16.h>

#define DEV __device__ __forceinline__

DEV float lrelu_(float x){ return x > 0.f ? x : 0.01f * x; }
DEV float ssp_(float x){ return fmaxf(x, 0.f) + __logf(1.f + __expf(-fabsf(x))) - 0.69314718055994530942f; }
DEV float sigm_(float x){ return 1.f / (1.f + __expf(-x)); }

DEV unsigned short f2bf(float x){
    unsigned int u = __float_as_uint(x);
    unsigned int r = (u + 0x7FFFu + ((u >> 16) & 1u)) >> 16;
    return (unsigned short)r;
}
DEV float bf2f(unsigned short s){ return __uint_as_float((unsigned int)s << 16); }
DEV ushort4 pack4(float4 v){
    ushort4 u; u.x = f2bf(v.x); u.y = f2bf(v.y); u.z = f2bf(v.z); u.w = f2bf(v.w); return u;
}

DEV void fma44(float (&acc)[4][4], const float4 (&xa)[4], const float4 (&wa)[4])
{
    #pragma unroll
    for (int kk = 0; kk < 4; kk++) {
        #pragma unroll
        for (int i = 0; i < 4; i++) {
            float x = ((const float*)&xa[i])[kk];
            #pragma unroll
            for (int j = 0; j < 4; j++)
                acc[i][j] += x * ((const float*)&wa[kk])[j];
        }
    }
}

typedef short s8v __attribute__((ext_vector_type(8)));
typedef float f4v __attribute__((ext_vector_type(4)));

// ====== generic tiled GEMM (VALU, small K): Y[N x 64] = act(X @ W[K x 64] + b) ======
template<int K, int ACT, bool OUTBF>
__global__ __launch_bounds__(256) void gemm64_kernel(const float* __restrict__ X,
                                                     const float* __restrict__ W,
                                                     const float* __restrict__ B,
                                                     void* __restrict__ Yv, int nrows)
{
    constexpr int XS = K + 4;
    constexpr int KQ = K / 4;
    __shared__ float Ws[K * 64];
    __shared__ float bs[64];
    __shared__ float Xs[64 * XS];
    for (int i = threadIdx.x; i < K * 64; i += 256) Ws[i] = W[i];
    if (threadIdx.x < 64) bs[threadIdx.x] = B[threadIdx.x];
    const int tr = threadIdx.x >> 4, tc = threadIdx.x & 15;
    const int r0 = tr * 4, c0 = tc * 4;
    for (int base = blockIdx.x * 64; base < nrows; base += gridDim.x * 64) {
        __syncthreads();
        for (int i = threadIdx.x; i < 64 * KQ; i += 256) {
            int row = i / KQ, kq = (i % KQ) * 4;
            int g = base + row;
            float4 v = make_float4(0.f, 0.f, 0.f, 0.f);
            if (g < nrows) v = *(const float4*)&X[(size_t)g * K + kq];
            *(float4*)&Xs[row * XS + kq] = v;
        }
        __syncthreads();
        float acc[4][4];
        #pragma unroll
        for (int i = 0; i < 4; i++)
            #pragma unroll
            for (int j = 0; j < 4; j++) acc[i][j] = bs[c0 + j];
        #pragma unroll 4
        for (int kq = 0; kq < K; kq += 4) {
            float4 xa[4], wa[4];
            #pragma unroll
            for (int i = 0; i < 4; i++) xa[i] = *(const float4*)&Xs[(r0 + i) * XS + kq];
            #pragma unroll
            for (int j = 0; j < 4; j++) wa[j] = *(const float4*)&Ws[(kq + j) * 64 + c0];
            fma44(acc, xa, wa);
        }
        #pragma unroll
        for (int i = 0; i < 4; i++) {
            int g = base + r0 + i;
            if (g < nrows) {
                float4 o;
                float* op = (float*)&o;
                #pragma unroll
                for (int j = 0; j < 4; j++) {
                    float a = acc[i][j];
                    if (ACT == 1) a = lrelu_(a);
                    else if (ACT == 2) a = fmaxf(a, 0.f);
                    op[j] = a;
                }
                if (OUTBF) *(ushort4*)&((unsigned short*)Yv)[(size_t)g * 64 + c0] = pack4(o);
                else       *(float4*)&((float*)Yv)[(size_t)g * 64 + c0] = o;
            }
        }
    }
}

// ====== MFMA GEMM: Y = act(X @ W64x64 + b); INBF/OUTBF select bf16 storage ======
template<int ACT, bool INBF, bool OUTBF>
__global__ __launch_bounds__(256) void mfma_gemm_kernel(const void* __restrict__ Xv,
                                                        const float* __restrict__ W,
                                                        const float* __restrict__ B,
                                                        void* __restrict__ Yv, int nrows)
{
    __shared__ __align__(16) unsigned short WT[64 * 72];   // [n][k]
    __shared__ __align__(16) unsigned short Axs[64 * 72];  // [row][k]
    __shared__ float bs[64];
    for (int i = threadIdx.x; i < 4096; i += 256) {
        int k = i >> 6, nn = i & 63;
        WT[nn * 72 + k] = f2bf(W[i]);
    }
    if (threadIdx.x < 64) bs[threadIdx.x] = B[threadIdx.x];
    const int lane = threadIdx.x & 63, wv = threadIdx.x >> 6;
    const int l15 = lane & 15, quad = lane >> 4;
    const int arow = 16 * wv + l15;
    const int koff = quad * 8;
    for (int base = blockIdx.x * 64; base < nrows; base += gridDim.x * 64) {
        __syncthreads();
        {
            int row = threadIdx.x >> 2, kq = (threadIdx.x & 3) * 16;
            int g = base + row;
            if (INBF) {
                const unsigned short* Xb = (const unsigned short*)Xv;
                uint4 v0 = make_uint4(0,0,0,0), v1 = v0;
                if (g < nrows) {
                    v0 = *(const uint4*)&Xb[(size_t)g * 64 + kq];
                    v1 = *(const uint4*)&Xb[(size_t)g * 64 + kq + 8];
                }
                *(uint4*)&Axs[row * 72 + kq] = v0;
                *(uint4*)&Axs[row * 72 + kq + 8] = v1;
            } else {
                const float* Xf = (const float*)Xv;
                #pragma unroll
                for (int m = 0; m < 4; m++) {
                    float4 v = make_float4(0,0,0,0);
                    if (g < nrows) v = *(const float4*)&Xf[(size_t)g * 64 + kq + m * 4];
                    *(ushort4*)&Axs[row * 72 + kq + m * 4] = pack4(v);
                }
            }
        }
        __syncthreads();
        f4v acc[4];
        #pragma unroll
        for (int t = 0; t < 4; t++) acc[t] = (f4v){0.f,0.f,0.f,0.f};
        s8v a0 = *(const s8v*)&Axs[arow * 72 + koff];
        s8v a1 = *(const s8v*)&Axs[arow * 72 + 32 + koff];
        #pragma unroll
        for (int t = 0; t < 4; t++) {
            int nn = t * 16 + l15;
            s8v b0 = *(const s8v*)&WT[nn * 72 + koff];
            s8v b1 = *(const s8v*)&WT[nn * 72 + 32 + koff];
            acc[t] = __builtin_amdgcn_mfma_f32_16x16x32_bf16(a0, b0, acc[t], 0, 0, 0);
            acc[t] = __builtin_amdgcn_mfma_f32_16x16x32_bf16(a1, b1, acc[t], 0, 0, 0);
        }
        const int mrow = 16 * wv + quad * 4;
        #pragma unroll
        for (int t = 0; t < 4; t++) {
            int col = t * 16 + l15;
            float b = bs[col];
            #pragma unroll
            for (int r = 0; r < 4; r++) {
                int g = base + mrow + r;
                if (g < nrows) {
                    float a = acc[t][r] + b;
                    if (ACT == 1) a = lrelu_(a);
                    else if (ACT == 2) a = fmaxf(a, 0.f);
                    if (OUTBF) ((unsigned short*)Yv)[(size_t)g * 64 + col] = f2bf(a);
                    else       ((float*)Yv)[(size_t)g * 64 + col] = a;
                }
            }
        }
    }
}

// ====== MFMA triple-GEMM combine (cf input fp32, others bf16) ======
__global__ __launch_bounds__(256) void mfma_combine_kernel(const float* __restrict__ cff,
                                                           const unsigned short* __restrict__ nfb,
                                                           const unsigned short* __restrict__ ngb,
                                                           const float* __restrict__ Wc, const float* __restrict__ cB,
                                                           const float* __restrict__ sW, const float* __restrict__ nW,
                                                           const float* __restrict__ sB,
                                                           unsigned short* __restrict__ outb, int n)
{
    __shared__ __align__(16) unsigned short WcT[64 * 72], WsT[64 * 72], WnT[64 * 72];
    __shared__ __align__(16) unsigned short Ac[32 * 72], As[32 * 72], An[32 * 72];
    __shared__ float bc[64], bsg[64];
    for (int i = threadIdx.x; i < 4096; i += 256) {
        int k = i >> 6, nn = i & 63;
        WcT[nn * 72 + k] = f2bf(Wc[i]);
        WsT[nn * 72 + k] = f2bf(sW[i]);
        WnT[nn * 72 + k] = f2bf(nW[i]);
    }
    if (threadIdx.x < 64) { bc[threadIdx.x] = cB[threadIdx.x]; bsg[threadIdx.x] = sB[threadIdx.x]; }
    const int lane = threadIdx.x & 63, wv = threadIdx.x >> 6;
    const int l15 = lane & 15, quad = lane >> 4;
    const int arow = (wv & 1) * 16 + l15;
    const int ct0 = (wv >> 1) * 2;
    const int koff = quad * 8;
    for (int base = blockIdx.x * 32; base < n; base += gridDim.x * 32) {
        __syncthreads();
        {
            int row = threadIdx.x >> 3, kq = (threadIdx.x & 7) * 8;
            int g = base + row;
            uint4 vf = make_uint4(0,0,0,0), vg = vf;
            float4 c0 = make_float4(0,0,0,0), c1 = c0;
            if (g < n) {
                c0 = *(const float4*)&cff[(size_t)g * 64 + kq];
                c1 = *(const float4*)&cff[(size_t)g * 64 + kq + 4];
                vf = *(const uint4*)&nfb[(size_t)g * 64 + kq];
                vg = *(const uint4*)&ngb[(size_t)g * 64 + kq];
            }
            *(ushort4*)&Ac[row * 72 + kq]     = pack4(c0);
            *(ushort4*)&Ac[row * 72 + kq + 4] = pack4(c1);
            *(uint4*)&As[row * 72 + kq] = vf;
            *(uint4*)&An[row * 72 + kq] = vg;
        }
        __syncthreads();
        f4v accC[2], accS[2];
        #pragma unroll
        for (int t = 0; t < 2; t++) { accC[t] = (f4v){0.f,0.f,0.f,0.f}; accS[t] = (f4v){0.f,0.f,0.f,0.f}; }
        s8v ac0 = *(const s8v*)&Ac[arow * 72 + koff];
        s8v ac1 = *(const s8v*)&Ac[arow * 72 + 32 + koff];
        s8v as0 = *(const s8v*)&As[arow * 72 + koff];
        s8v as1 = *(const s8v*)&As[arow * 72 + 32 + koff];
        s8v an0 = *(const s8v*)&An[arow * 72 + koff];
        s8v an1 = *(const s8v*)&An[arow * 72 + 32 + koff];
        #pragma unroll
        for (int t = 0; t < 2; t++) {
            int nn = (ct0 + t) * 16 + l15;
            s8v wc0 = *(const s8v*)&WcT[nn * 72 + koff];
            s8v wc1 = *(const s8v*)&WcT[nn * 72 + 32 + koff];
            accC[t] = __builtin_amdgcn_mfma_f32_16x16x32_bf16(ac0, wc0, accC[t], 0, 0, 0);
            accC[t] = __builtin_amdgcn_mfma_f32_16x16x32_bf16(ac1, wc1, accC[t], 0, 0, 0);
            s8v ws0 = *(const s8v*)&WsT[nn * 72 + koff];
            s8v ws1 = *(const s8v*)&WsT[nn * 72 + 32 + koff];
            accS[t] = __builtin_amdgcn_mfma_f32_16x16x32_bf16(as0, ws0, accS[t], 0, 0, 0);
            accS[t] = __builtin_amdgcn_mfma_f32_16x16x32_bf16(as1, ws1, accS[t], 0, 0, 0);
            s8v wn0 = *(const s8v*)&WnT[nn * 72 + koff];
            s8v wn1 = *(const s8v*)&WnT[nn * 72 + 32 + koff];
            accS[t] = __builtin_amdgcn_mfma_f32_16x16x32_bf16(an0, wn0, accS[t], 0, 0, 0);
            accS[t] = __builtin_amdgcn_mfma_f32_16x16x32_bf16(an1, wn1, accS[t], 0, 0, 0);
        }
        const int mrow = (wv & 1) * 16 + quad * 4;
        #pragma unroll
        for (int t = 0; t < 2; t++) {
            int col = (ct0 + t) * 16 + l15;
            float bcv = bc[col], bsv = bsg[col];
            #pragma unroll
            for (int r = 0; r < 4; r++) {
                int g = base + mrow + r;
                if (g < n)
                    outb[(size_t)g * 64 + col] = f2bf(lrelu_(fmaxf(ssp_(accC[t][r] + bcv), accS[t][r] + bsv)));
            }
        }
    }
}

// ---------------- small scalar GEMV (pin encoder, C=16) ----------------
template<int K, int C, int ACT, bool OUTBF>
__global__ __launch_bounds__(256) void lin_kernel(const float* __restrict__ X,
                                                  const float* __restrict__ W,
                                                  const float* __restrict__ B,
                                                  void* __restrict__ Yv, int nrows)
{
    constexpr int ROWS = 256 / C;
    __shared__ float Ws[K * C];
    __shared__ float bs[C];
    __shared__ float Xs[ROWS * K];
    for (int i = threadIdx.x; i < K * C; i += 256) Ws[i] = W[i];
    if (threadIdx.x < C) bs[threadIdx.x] = B[threadIdx.x];
    __syncthreads();
    const int r = threadIdx.x / C, c = threadIdx.x % C;
    for (int base = blockIdx.x * ROWS; base < nrows; base += gridDim.x * ROWS) {
        __syncthreads();
        for (int i = threadIdx.x; i < ROWS * K; i += 256) {
            int rr = base + i / K;
            Xs[i] = (rr < nrows) ? X[(size_t)rr * K + i % K] : 0.f;
        }
        __syncthreads();
        int row = base + r;
        if (row < nrows) {
            float acc = bs[c];
            #pragma unroll
            for (int k = 0; k < K; k++) acc += Xs[r * K + k] * Ws[k * C + c];
            if (ACT == 1) acc = lrelu_(acc);
            else if (ACT == 2) acc = fmaxf(acc, 0.f);
            if (OUTBF) ((unsigned short*)Yv)[(size_t)row * C + c] = f2bf(acc);
            else       ((float*)Yv)[(size_t)row * C + c] = acc;
        }
    }
}

// ---------------- degrees: counts into cnt (psrc, Nn) and pcnt (pdst, Nt) ----------------
__global__ __launch_bounds__(256) void deg_kernel(const int* __restrict__ src, const int* __restrict__ dst,
                                                  int* __restrict__ cnt_src, int* __restrict__ cnt_dst, int np)
{
    int p = blockIdx.x * 256 + threadIdx.x;
    if (p < np) { atomicAdd(&cnt_src[src[p]], 1); atomicAdd(&cnt_dst[dst[p]], 1); }
}

// norm_out: out = rsqrt(max(cnt,1)) — non-destructive (counts reused by scans)
__global__ __launch_bounds__(256) void norm_out_kernel(const int* __restrict__ cnt, float* __restrict__ out, int n)
{
    int i = blockIdx.x * 256 + threadIdx.x;
    if (i < n) {
        int v = cnt[i]; if (v < 1) v = 1;
        out[i] = rsqrtf((float)v);
    }
}

// ================= CSR build (generic, keyed by given index array) =================
__global__ __launch_bounds__(256) void csr_count_kernel(const int* __restrict__ key, int* __restrict__ cnt, int ne)
{
    int e = blockIdx.x * 256 + threadIdx.x;
    if (e < ne) atomicAdd(&cnt[key[e]], 1);
}

__global__ __launch_bounds__(256) void scan_block_sum_kernel(const int* __restrict__ cnt, int* __restrict__ bsum, int n)
{
    __shared__ int sh[256];
    int i = blockIdx.x * 256 + threadIdx.x;
    sh[threadIdx.x] = (i < n) ? cnt[i] : 0;
    __syncthreads();
    for (int s = 128; s > 0; s >>= 1) {
        if (threadIdx.x < s) sh[threadIdx.x] += sh[threadIdx.x + s];
        __syncthreads();
    }
    if (threadIdx.x == 0) bsum[blockIdx.x] = sh[0];
}

__global__ __launch_bounds__(512) void scan_bsum_kernel(int* __restrict__ bsum, int nb, int* __restrict__ total_out)
{
    __shared__ int sh[512];
    int i = threadIdx.x;
    int v = (i < nb) ? bsum[i] : 0;
    sh[i] = v;
    __syncthreads();
    for (int s = 1; s < 512; s <<= 1) {
        int add = (i >= s) ? sh[i - s] : 0;
        __syncthreads();
        sh[i] += add;
        __syncthreads();
    }
    if (i < nb) bsum[i] = sh[i] - v;     // exclusive
    if (i == nb - 1) *total_out = sh[i];
}

__global__ __launch_bounds__(256) void scan_final_kernel(const int* __restrict__ cnt, const int* __restrict__ bsum,
                                                         int* __restrict__ row_start, int* __restrict__ nxt, int n)
{
    __shared__ int sh[256];
    int i = blockIdx.x * 256 + threadIdx.x;
    int v = (i < n) ? cnt[i] : 0;
    sh[threadIdx.x] = v;
    __syncthreads();
    for (int s = 1; s < 256; s <<= 1) {
        int add = (threadIdx.x >= s) ? sh[threadIdx.x - s] : 0;
        __syncthreads();
        sh[threadIdx.x] += add;
        __syncthreads();
    }
    if (i < n) {
        int excl = sh[threadIdx.x] - v + bsum[blockIdx.x];
        row_start[i] = excl;
        nxt[i] = excl;
    }
}

// XCD-colored CSR fill (see R2)
__global__ __launch_bounds__(256) void csr_fill_kernel(const int* __restrict__ key, int* __restrict__ nxt,
                                                       int* __restrict__ eidx, int ne, int nrows)
{
    const int color = blockIdx.x & 7;
    const int bid = blockIdx.x >> 3;
    const int nblk = gridDim.x >> 3;
    const int lo = (int)(((long long)nrows * color) >> 3);
    const int hi = (int)(((long long)nrows * (color + 1)) >> 3);
    for (int e = bid * 256 + threadIdx.x; e < ne; e += nblk * 256) {
        int k = key[e];
        if (k >= lo && k < hi) {
            int slot = atomicAdd(&nxt[k], 1);
            eidx[slot] = e;
        }
    }
}

// ---------------- pin feature permutation into psrc-CSR slot order ----------------
// Also emits pdst_s (dst per slot) and snode_s (owning node per slot, non-decreasing).
__global__ __launch_bounds__(256) void pin_permute_kernel(const int* __restrict__ seidx,
                                                          const unsigned short* __restrict__ pinb,
                                                          const int* __restrict__ pdst,
                                                          const int* __restrict__ psrc,
                                                          unsigned short* __restrict__ pinb_s,
                                                          int* __restrict__ pdst_s,
                                                          int* __restrict__ snode_s, int np)
{
    int slot = blockIdx.x * 256 + threadIdx.x;
    if (slot < np) {
        int p = seidx[slot];
        uint4 a = *(const uint4*)&pinb[(size_t)p * 16];
        uint4 b = *(const uint4*)&pinb[(size_t)p * 16 + 8];
        *(uint4*)&pinb_s[(size_t)slot * 16] = a;
        *(uint4*)&pinb_s[(size_t)slot * 16 + 8] = b;
        pdst_s[slot] = pdst[p];
        snode_s[slot] = psrc[p];
    }
}

// ---------------- pins-dst CSR metadata permutation: psrc_s/snorm_s in peidx slot order -------
__global__ __launch_bounds__(256) void pins_meta_permute_kernel(const int* __restrict__ peidx,
                                                                const int* __restrict__ psrc,
                                                                const float* __restrict__ snorm,
                                                                int* __restrict__ psrc_s,
                                                                float* __restrict__ snorm_s, int np)
{
    int slot = blockIdx.x * 256 + threadIdx.x;
    if (slot < np) {
        int s = psrc[peidx[slot]];
        psrc_s[slot] = s;
        snorm_s[slot] = snorm[s];
    }
}

// ---------------- near CSR metadata permutation: esrc_s in eidx slot order ----------------
__global__ __launch_bounds__(256) void near_meta_permute_kernel(const int* __restrict__ eidx,
                                                                const int* __restrict__ esrc,
                                                                int* __restrict__ esrc_s, int ne)
{
    int slot = blockIdx.x * 256 + threadIdx.x;
    if (slot < ne) esrc_s[slot] = esrc[eidx[slot]];
}

// ---------------- edge weights for all 3 layers ----------------
__global__ __launch_bounds__(256) void edge_ew_kernel(const float* __restrict__ in_edge,
                                                      const float* __restrict__ elW, const float* __restrict__ elb,
                                                      const float* __restrict__ gW, const float* __restrict__ gb,
                                                      float* __restrict__ ew3, int ne)
{
    __shared__ float W[32], B[8], G[24], Gb[3];
    if (threadIdx.x < 32) W[threadIdx.x] = elW[threadIdx.x];
    if (threadIdx.x < 8)  B[threadIdx.x] = elb[threadIdx.x];
    if (threadIdx.x < 24) G[threadIdx.x] = gW[threadIdx.x];
    if (threadIdx.x < 3)  Gb[threadIdx.x] = gb[threadIdx.x];
    __syncthreads();
    for (int e = blockIdx.x * 256 + threadIdx.x; e < ne; e += gridDim.x * 256) {
        float4 x = *(const float4*)&in_edge[(size_t)e * 4];
        float ef[8];
        #pragma unroll
        for (int j = 0; j < 8; j++)
            ef[j] = lrelu_(B[j] + x.x * W[j] + x.y * W[8 + j] + x.z * W[16 + j] + x.w * W[24 + j]);
        #pragma unroll
        for (int i = 0; i < 3; i++) {
            float a = Gb[i];
            #pragma unroll
            for (int j = 0; j < 8; j++) a += ef[j] * G[i * 8 + j];
            ew3[(size_t)i * ne + e] = sigm_(a);
        }
    }
}

// ---------------- pins GraphConv gather (slot-ordered metadata, unroll-8) -------------
__global__ __launch_bounds__(256) void pins_gather_kernel(const unsigned short* __restrict__ nfb,
                                                          const float* __restrict__ dnorm,
                                                          const int* __restrict__ psrc_s,
                                                          const float* __restrict__ snorm_s,
                                                          const int* __restrict__ prow,
                                                          unsigned short* __restrict__ aggb, int nt)
{
    __shared__ int sS[4][64];
    __shared__ float sN[4][64];
    const int lane = threadIdx.x & 63, wv = threadIdx.x >> 6;
    for (int d = blockIdx.x * 4 + wv; d < nt; d += gridDim.x * 4) {
        int rs = prow[d], re = prow[d + 1];
        float acc = 0.f;
        for (int cbase = rs; cbase < re; cbase += 64) {
            int cnt = re - cbase; if (cnt > 64) cnt = 64;
            if (lane < cnt) {
                sS[wv][lane] = psrc_s[cbase + lane];
                sN[wv][lane] = snorm_s[cbase + lane];
            }
            int k = 0;
            for (; k + 7 < cnt; k += 8) {
                float v[8];
                #pragma unroll
                for (int j = 0; j < 8; j++)
                    v[j] = bf2f(nfb[(size_t)sS[wv][k + j] * 64 + lane]) * sN[wv][k + j];
                acc += ((v[0] + v[1]) + (v[2] + v[3])) + ((v[4] + v[5]) + (v[6] + v[7]));
            }
            for (; k + 3 < cnt; k += 4) {
                float v0 = bf2f(nfb[(size_t)sS[wv][k]   * 64 + lane]) * sN[wv][k];
                float v1 = bf2f(nfb[(size_t)sS[wv][k+1] * 64 + lane]) * sN[wv][k+1];
                float v2 = bf2f(nfb[(size_t)sS[wv][k+2] * 64 + lane]) * sN[wv][k+2];
                float v3 = bf2f(nfb[(size_t)sS[wv][k+3] * 64 + lane]) * sN[wv][k+3];
                acc += (v0 + v1) + (v2 + v3);
            }
            for (; k < cnt; k++)
                acc += bf2f(nfb[(size_t)sS[wv][k] * 64 + lane]) * sN[wv][k];
        }
        aggb[(size_t)d * 64 + lane] = f2bf(acc * dnorm[d]);
    }
}

// ---------------- FUSED CFConv: per-slot HE (MFMA, in LDS) + immediate gather-accumulate ------
// HE tile stays in LDS; wave wv consumes its own 16 rows (it wrote them) multiplying by
// hv[pdst_s[slot]] and run-accumulating per node (snode_s non-decreasing); one f32
// atomicAdd per (node-run, lane) into cff. Eliminates the 50MB HE write + 51MB re-read.
__global__ __launch_bounds__(256) void cf_fused_kernel(const unsigned short* __restrict__ pinb,
                                                       const float* __restrict__ W1, const float* __restrict__ B1,
                                                       const float* __restrict__ W2, const float* __restrict__ B2,
                                                       const unsigned short* __restrict__ hvb,
                                                       const int* __restrict__ pdst_s,
                                                       const int* __restrict__ snode_s,
                                                       float* __restrict__ cff, int np)
{
    __shared__ __align__(16) unsigned short W1T[64 * 40];  // B operand [n][k], k 0..31 (16..31 zero)
    __shared__ __align__(16) unsigned short W2T[64 * 72];
    __shared__ __align__(16) unsigned short PFb[64 * 40];  // A rows [p][k 0..31], padded zeros
    __shared__ __align__(16) unsigned short T1s[64 * 72];  // T1 then HE
    __shared__ float bs1[64], bs2[64];
    for (int i = threadIdx.x; i < 64 * 32; i += 256) {
        int n = i & 63, k = i >> 6;
        W1T[n * 40 + k] = (k < 16) ? f2bf(W1[k * 64 + n]) : (unsigned short)0;
    }
    for (int i = threadIdx.x; i < 4096; i += 256) {
        int k = i >> 6, n = i & 63;
        W2T[n * 72 + k] = f2bf(W2[i]);
    }
    if (threadIdx.x < 64) { bs1[threadIdx.x] = B1[threadIdx.x]; bs2[threadIdx.x] = B2[threadIdx.x]; }
    const int lane = threadIdx.x & 63, wv = threadIdx.x >> 6;
    const int l15 = lane & 15, quad = lane >> 4;
    const int arow = 16 * wv + l15;
    const int koff = quad * 8;
    const int mrow = 16 * wv + quad * 4;
    for (int base = blockIdx.x * 64; base < np; base += gridDim.x * 64) {
        __syncthreads();
        {
            int row = threadIdx.x >> 2, q = threadIdx.x & 3;
            int p = base + row;
            uint2 v = make_uint2(0, 0);
            if (p < np) v = *(const uint2*)&pinb[(size_t)p * 16 + q * 4];
            *(uint2*)&PFb[row * 40 + q * 4] = v;
            if (q < 2)
                *(uint4*)&PFb[row * 40 + 16 + q * 8] = make_uint4(0,0,0,0);
        }
        __syncthreads();
        // GEMM1 (MFMA, K=32 zero-padded): T1 = ssp(PF @ W1 + b1)
        {
            f4v acc1[4];
            #pragma unroll
            for (int t = 0; t < 4; t++) acc1[t] = (f4v){0.f,0.f,0.f,0.f};
            s8v a = *(const s8v*)&PFb[arow * 40 + koff];
            #pragma unroll
            for (int t = 0; t < 4; t++) {
                int n = t * 16 + l15;
                s8v b = *(const s8v*)&W1T[n * 40 + koff];
                acc1[t] = __builtin_amdgcn_mfma_f32_16x16x32_bf16(a, b, acc1[t], 0, 0, 0);
            }
            #pragma unroll
            for (int t = 0; t < 4; t++) {
                int col = t * 16 + l15;
                float b = bs1[col];
                #pragma unroll
                for (int r = 0; r < 4; r++)
                    T1s[(mrow + r) * 72 + col] = f2bf(ssp_(acc1[t][r] + b));
            }
        }
        __syncthreads();
        // GEMM2 (MFMA): HE = ssp(T1 @ W2 + b2); overwrites T1s (guarded)
        {
            f4v acc4[4];
            #pragma unroll
            for (int t = 0; t < 4; t++) acc4[t] = (f4v){0.f, 0.f, 0.f, 0.f};
            s8v a0 = *(const s8v*)&T1s[arow * 72 + koff];
            s8v a1 = *(const s8v*)&T1s[arow * 72 + 32 + koff];
            #pragma unroll
            for (int t = 0; t < 4; t++) {
                int n = t * 16 + l15;
                s8v b0 = *(const s8v*)&W2T[n * 72 + koff];
                s8v b1 = *(const s8v*)&W2T[n * 72 + 32 + koff];
                acc4[t] = __builtin_amdgcn_mfma_f32_16x16x32_bf16(a0, b0, acc4[t], 0, 0, 0);
                acc4[t] = __builtin_amdgcn_mfma_f32_16x16x32_bf16(a1, b1, acc4[t], 0, 0, 0);
            }
            __syncthreads();
            #pragma unroll
            for (int t = 0; t < 4; t++) {
                int col = t * 16 + l15;
                float b = bs2[col];
                #pragma unroll
                for (int r = 0; r < 4; r++)
                    T1s[(mrow + r) * 72 + col] = f2bf(ssp_(acc4[t][r] + b));
            }
        }
        __syncthreads();
        // fused gather: wave wv consumes slots [base+16wv, base+16wv+16)
        {
            int s0 = base + wv * 16;
            if (s0 < np) {
                int cur = snode_s[s0];
                float acc = 0.f;
                #pragma unroll 4
                for (int k = 0; k < 16; k++) {
                    int slot = s0 + k;
                    if (slot >= np) break;
                    int node = snode_s[slot];
                    float he = bf2f(T1s[(wv * 16 + k) * 72 + lane]);
                    float hv = bf2f(hvb[(size_t)pdst_s[slot] * 64 + lane]);
                    if (node != cur) {
                        atomicAdd(&cff[(size_t)cur * 64 + lane], acc);
                        acc = 0.f;
                        cur = node;
                    }
                    acc += he * hv;
                }
                atomicAdd(&cff[(size_t)cur * 64 + lane], acc);
            }
        }
    }
}

// ---------------- SAGE gather-max (slot-ordered esrc, unroll-8) ----------------
__global__ __launch_bounds__(256) void sage_gather_kernel(const unsigned short* __restrict__ hpb,
                                                          const float* __restrict__ ew,
                                                          const int* __restrict__ esrc_s,
                                                          const int* __restrict__ row_start,
                                                          const int* __restrict__ eidx,
                                                          unsigned short* __restrict__ ngb, int nn)
{
    __shared__ int sS[4][64];
    __shared__ float sWt[4][64];
    const int lane = threadIdx.x & 63, wv = threadIdx.x >> 6;
    for (int d = blockIdx.x * 4 + wv; d < nn; d += gridDim.x * 4) {
        int rs = row_start[d], re = row_start[d + 1];
        float acc = 0.f;
        for (int cbase = rs; cbase < re; cbase += 64) {
            int cnt = re - cbase; if (cnt > 64) cnt = 64;
            if (lane < cnt) {
                sS[wv][lane] = esrc_s[cbase + lane];
                sWt[wv][lane] = ew[eidx[cbase + lane]];
            }
            int k = 0;
            for (; k + 7 < cnt; k += 8) {
                float v[8];
                #pragma unroll
                for (int j = 0; j < 8; j++)
                    v[j] = bf2f(hpb[(size_t)sS[wv][k + j] * 64 + lane]) * sWt[wv][k + j];
                float m0 = fmaxf(fmaxf(v[0], v[1]), fmaxf(v[2], v[3]));
                float m1 = fmaxf(fmaxf(v[4], v[5]), fmaxf(v[6], v[7]));
                acc = fmaxf(acc, fmaxf(m0, m1));
            }
            for (; k + 3 < cnt; k += 4) {
                float v0 = bf2f(hpb[(size_t)sS[wv][k]   * 64 + lane]) * sWt[wv][k];
                float v1 = bf2f(hpb[(size_t)sS[wv][k+1] * 64 + lane]) * sWt[wv][k+1];
                float v2 = bf2f(hpb[(size_t)sS[wv][k+2] * 64 + lane]) * sWt[wv][k+2];
                float v3 = bf2f(hpb[(size_t)sS[wv][k+3] * 64 + lane]) * sWt[wv][k+3];
                acc = fmaxf(acc, fmaxf(fmaxf(v0, v1), fmaxf(v2, v3)));
            }
            for (; k < cnt; k++)
                acc = fmaxf(acc, bf2f(hpb[(size_t)sS[wv][k] * 64 + lane]) * sWt[wv][k]);
        }
        ngb[(size_t)d * 64 + lane] = f2bf(acc);
    }
}

// ---------------- node head (MFMA, 64 rows/tile, 3-stage MLP 80->64->64->4) ----------------
__global__ __launch_bounds__(256) void node_head_mfma_kernel(const float* __restrict__ in_node,
                                                             const unsigned short* __restrict__ nfb,
                                                             const float* __restrict__ W1, const float* __restrict__ B1,
                                                             const float* __restrict__ W2, const float* __restrict__ B2,
                                                             const float* __restrict__ W3, const float* __restrict__ B3,
                                                             float* __restrict__ out, int n)
{
    __shared__ __align__(16) unsigned short W1T[64 * 104];  // [n][k 0..95], k>=80 zero
    __shared__ __align__(16) unsigned short W2T[64 * 72];
    __shared__ __align__(16) unsigned short W3T[16 * 72];   // [c][k], c>=4 zero
    __shared__ __align__(16) unsigned short Xs[64 * 104];   // A rows; reused as H2 [64*72]
    __shared__ __align__(16) unsigned short H1[64 * 72];
    __shared__ float bs1[64], bs2[64], bs3[4];
    for (int i = threadIdx.x; i < 64 * 96; i += 256) {
        int k = i >> 6, nn = i & 63;
        W1T[nn * 104 + k] = (k < 80) ? f2bf(W1[k * 64 + nn]) : (unsigned short)0;
    }
    for (int i = threadIdx.x; i < 4096; i += 256) {
        int k = i >> 6, nn = i & 63;
        W2T[nn * 72 + k] = f2bf(W2[i]);
    }
    for (int i = threadIdx.x; i < 1024; i += 256) {
        int k = i >> 4, c = i & 15;
        W3T[c * 72 + k] = (c < 4) ? f2bf(W3[k * 4 + c]) : (unsigned short)0;
    }
    if (threadIdx.x < 64) { bs1[threadIdx.x] = B1[threadIdx.x]; bs2[threadIdx.x] = B2[threadIdx.x]; }
    if (threadIdx.x < 4) bs3[threadIdx.x] = B3[threadIdx.x];
    const int lane = threadIdx.x & 63, wv = threadIdx.x >> 6;
    const int l15 = lane & 15, quad = lane >> 4;
    const int arow = 16 * wv + l15;
    const int koff = quad * 8;
    const int mrow = 16 * wv + quad * 4;
    unsigned short* H2 = Xs;  // stride 72, fits inside 64*104 region
    for (int base = blockIdx.x * 64; base < n; base += gridDim.x * 64) {
        __syncthreads();
        {
            int row = threadIdx.x >> 2, q = threadIdx.x & 3;
            int g = base + row;
            float4 v = make_float4(0,0,0,0);
            if (g < n) v = *(const float4*)&in_node[(size_t)g * 16 + q * 4];
            *(ushort4*)&Xs[row * 104 + q * 4] = pack4(v);
            uint4 u0 = make_uint4(0,0,0,0), u1 = u0;
            if (g < n) {
                u0 = *(const uint4*)&nfb[(size_t)g * 64 + q * 16];
                u1 = *(const uint4*)&nfb[(size_t)g * 64 + q * 16 + 8];
            }
            *(uint4*)&Xs[row * 104 + 16 + q * 16] = u0;
            *(uint4*)&Xs[row * 104 + 16 + q * 16 + 8] = u1;
            ushort4 z; z.x = 0; z.y = 0; z.z = 0; z.w = 0;
            *(ushort4*)&Xs[row * 104 + 80 + q * 4] = z;  // pad k 80..95
        }
        __syncthreads();
        // GEMM1: H1 = lrelu(X @ W1 + b1), K=96
        {
            f4v acc[4];
            #pragma unroll
            for (int t = 0; t < 4; t++) acc[t] = (f4v){0.f,0.f,0.f,0.f};
            s8v a0 = *(const s8v*)&Xs[arow * 104 + koff];
            s8v a1 = *(const s8v*)&Xs[arow * 104 + 32 + koff];
            s8v a2 = *(const s8v*)&Xs[arow * 104 + 64 + koff];
            #pragma unroll
            for (int t = 0; t < 4; t++) {
                int nn = t * 16 + l15;
                s8v b0 = *(const s8v*)&W1T[nn * 104 + koff];
                s8v b1 = *(const s8v*)&W1T[nn * 104 + 32 + koff];
                s8v b2 = *(const s8v*)&W1T[nn * 104 + 64 + koff];
                acc[t] = __builtin_amdgcn_mfma_f32_16x16x32_bf16(a0, b0, acc[t], 0, 0, 0);
                acc[t] = __builtin_amdgcn_mfma_f32_16x16x32_bf16(a1, b1, acc[t], 0, 0, 0);
                acc[t] = __builtin_amdgcn_mfma_f32_16x16x32_bf16(a2, b2, acc[t], 0, 0, 0);
            }
            #pragma unroll
            for (int t = 0; t < 4; t++) {
                int col = t * 16 + l15;
                float b = bs1[col];
                #pragma unroll
                for (int r = 0; r < 4; r++)
                    H1[(mrow + r) * 72 + col] = f2bf(lrelu_(acc[t][r] + b));
            }
        }
        __syncthreads();
        // GEMM2: H2 = lrelu(H1 @ W2 + b2), K=64; writes into Xs region
        {
            f4v acc[4];
            #pragma unroll
            for (int t = 0; t < 4; t++) acc[t] = (f4v){0.f,0.f,0.f,0.f};
            s8v a0 = *(const s8v*)&H1[arow * 72 + koff];
            s8v a1 = *(const s8v*)&H1[arow * 72 + 32 + koff];
            #pragma unroll
            for (int t = 0; t < 4; t++) {
                int nn = t * 16 + l15;
                s8v b0 = *(const s8v*)&W2T[nn * 72 + koff];
                s8v b1 = *(const s8v*)&W2T[nn * 72 + 32 + koff];
                acc[t] = __builtin_amdgcn_mfma_f32_16x16x32_bf16(a0, b0, acc[t], 0, 0, 0);
                acc[t] = __builtin_amdgcn_mfma_f32_16x16x32_bf16(a1, b1, acc[t], 0, 0, 0);
            }
            __syncthreads();   // all GEMM1 Xs reads done before overwriting
            #pragma unroll
            for (int t = 0; t < 4; t++) {
                int col = t * 16 + l15;
                float b = bs2[col];
                #pragma unroll
                for (int r = 0; r < 4; r++)
                    H2[(mrow + r) * 72 + col] = f2bf(lrelu_(acc[t][r] + b));
            }
        }
        __syncthreads();
        // GEMM3: out = sigm(H2 @ W3 + b3), 4 cols
        {
            f4v acc = (f4v){0.f,0.f,0.f,0.f};
            s8v a0 = *(const s8v*)&H2[arow * 72 + koff];
            s8v a1 = *(const s8v*)&H2[arow * 72 + 32 + koff];
            s8v b0 = *(const s8v*)&W3T[l15 * 72 + koff];
            s8v b1 = *(const s8v*)&W3T[l15 * 72 + 32 + koff];
            acc = __builtin_amdgcn_mfma_f32_16x16x32_bf16(a0, b0, acc, 0, 0, 0);
            acc = __builtin_amdgcn_mfma_f32_16x16x32_bf16(a1, b1, acc, 0, 0, 0);
            if (l15 < 4) {
                float b = bs3[l15];
                #pragma unroll
                for (int r = 0; r < 4; r++) {
                    int g = base + mrow + r;
                    if (g < n) out[(size_t)g * 4 + l15] = sigm_(acc[r] + b);
                }
            }
        }
    }
}

// ---------------- net head (MFMA, 64 rows/tile, 3-stage MLP 72->64->64->1) ----------------
__global__ __launch_bounds__(256) void net_head_mfma_kernel(const float* __restrict__ in_net, const float* __restrict__ tf,
                                                            const float* __restrict__ W1, const float* __restrict__ B1,
                                                            const float* __restrict__ W2, const float* __restrict__ B2,
                                                            const float* __restrict__ W3, const float* __restrict__ B3,
                                                            float* __restrict__ out, int n)
{
    __shared__ __align__(16) unsigned short W1T[64 * 104];  // [n][k 0..95], k>=72 zero
    __shared__ __align__(16) unsigned short W2T[64 * 72];
    __shared__ __align__(16) unsigned short W3T[16 * 72];   // [c][k], c>=1 zero
    __shared__ __align__(16) unsigned short Xs[64 * 104];   // reused as H2
    __shared__ __align__(16) unsigned short H1[64 * 72];
    __shared__ float bs1[64], bs2[64], bs3[1];
    for (int i = threadIdx.x; i < 64 * 96; i += 256) {
        int k = i >> 6, nn = i & 63;
        W1T[nn * 104 + k] = (k < 72) ? f2bf(W1[k * 64 + nn]) : (unsigned short)0;
    }
    for (int i = threadIdx.x; i < 4096; i += 256) {
        int k = i >> 6, nn = i & 63;
        W2T[nn * 72 + k] = f2bf(W2[i]);
    }
    for (int i = threadIdx.x; i < 1024; i += 256) {
        int k = i >> 4, c = i & 15;
        W3T[c * 72 + k] = (c == 0) ? f2bf(W3[k]) : (unsigned short)0;
    }
    if (threadIdx.x < 64) { bs1[threadIdx.x] = B1[threadIdx.x]; bs2[threadIdx.x] = B2[threadIdx.x]; }
    if (threadIdx.x == 0) bs3[0] = B3[0];
    const int lane = threadIdx.x & 63, wv = threadIdx.x >> 6;
    const int l15 = lane & 15, quad = lane >> 4;
    const int arow = 16 * wv + l15;
    const int koff = quad * 8;
    const int mrow = 16 * wv + quad * 4;
    unsigned short* H2 = Xs;
    for (int base = blockIdx.x * 64; base < n; base += gridDim.x * 64) {
        __syncthreads();
        {
            int row = threadIdx.x >> 2, q = threadIdx.x & 3;
            int g = base + row;
            if (q < 2) {
                float4 v = make_float4(0,0,0,0);
                if (g < n) v = *(const float4*)&in_net[(size_t)g * 8 + q * 4];
                *(ushort4*)&Xs[row * 104 + q * 4] = pack4(v);
            }
            #pragma unroll
            for (int m = 0; m < 4; m++) {
                float4 v = make_float4(0,0,0,0);
                if (g < n) v = *(const float4*)&tf[(size_t)g * 64 + q * 16 + m * 4];
                *(ushort4*)&Xs[row * 104 + 8 + q * 16 + m * 4] = pack4(v);
            }
            if (q < 3) {  // pad k 72..95
                ushort4 z; z.x = 0; z.y = 0; z.z = 0; z.w = 0;
                *(ushort4*)&Xs[row * 104 + 72 + q * 8] = z;
                *(ushort4*)&Xs[row * 104 + 72 + q * 8 + 4] = z;
            }
        }
        __syncthreads();
        {
            f4v acc[4];
            #pragma unroll
            for (int t = 0; t < 4; t++) acc[t] = (f4v){0.f,0.f,0.f,0.f};
            s8v a0 = *(const s8v*)&Xs[arow * 104 + koff];
            s8v a1 = *(const s8v*)&Xs[arow * 104 + 32 + koff];
            s8v a2 = *(const s8v*)&Xs[arow * 104 + 64 + koff];
            #pragma unroll
            for (int t = 0; t < 4; t++) {
                int nn = t * 16 + l15;
                s8v b0 = *(const s8v*)&W1T[nn * 104 + koff];
                s8v b1 = *(const s8v*)&W1T[nn * 104 + 32 + koff];
                s8v b2 = *(const s8v*)&W1T[nn * 104 + 64 + koff];
                acc[t] = __builtin_amdgcn_mfma_f32_16x16x32_bf16(a0, b0, acc[t], 0, 0, 0);
                acc[t] = __builtin_amdgcn_mfma_f32_16x16x32_bf16(a1, b1, acc[t], 0, 0, 0);
                acc[t] = __builtin_amdgcn_mfma_f32_16x16x32_bf16(a2, b2, acc[t], 0, 0, 0);
            }
            #pragma unroll
            for (int t = 0; t < 4; t++) {
                int col = t * 16 + l15;
                float b = bs1[col];
                #pragma unroll
                for (int r = 0; r < 4; r++)
                    H1[(mrow + r) * 72 + col] = f2bf(lrelu_(acc[t][r] + b));
            }
        }
        __syncthreads();
        {
            f4v acc[4];
            #pragma unroll
            for (int t = 0; t < 4; t++) acc[t] = (f4v){0.f,0.f,0.f,0.f};
            s8v a0 = *(const s8v*)&H1[arow * 72 + koff];
            s8v a1 = *(const s8v*)&H1[arow * 72 + 32 + koff];
            #pragma unroll
            for (int t = 0; t < 4; t++) {
                int nn = t * 16 + l15;
                s8v b0 = *(const s8v*)&W2T[nn * 72 + koff];
                s8v b1 = *(const s8v*)&W2T[nn * 72 + 32 + koff];
                acc[t] = __builtin_amdgcn_mfma_f32_16x16x32_bf16(a0, b0, acc[t], 0, 0, 0);
                acc[t] = __builtin_amdgcn_mfma_f32_16x16x32_bf16(a1, b1, acc[t], 0, 0, 0);
            }
            __syncthreads();
            #pragma unroll
            for (int t = 0; t < 4; t++) {
                int col = t * 16 + l15;
                float b = bs2[col];
                #pragma unroll
                for (int r = 0; r < 4; r++)
                    H2[(mrow + r) * 72 + col] = f2bf(lrelu_(acc[t][r] + b));
            }
        }
        __syncthreads();
        {
            f4v acc = (f4v){0.f,0.f,0.f,0.f};
            s8v a0 = *(const s8v*)&H2[arow * 72 + koff];
            s8v a1 = *(const s8v*)&H2[arow * 72 + 32 + koff];
            s8v b0 = *(const s8v*)&W3T[l15 * 72 + koff];
            s8v b1 = *(const s8v*)&W3T[l15 * 72 + 32 + koff];
            acc = __builtin_amdgcn_mfma_f32_16x16x32_bf16(a0, b0, acc, 0, 0, 0);
            acc = __builtin_amdgcn_mfma_f32_16x16x32_bf16(a1, b1, acc, 0, 0, 0);
            if (l15 == 0) {
                float b = bs3[0];
                #pragma unroll
                for (int r = 0; r < 4; r++) {
                    int g = base + mrow + r;
                    if (g < n) out[g] = sigm_(acc[r] + b);
                }
            }
        }
    }
}

extern "C" void kernel_launch(void* const* d_in, const int* in_sizes, int n_in,
                              void* d_out, int out_size, void* d_ws, size_t ws_size,
                              hipStream_t stream)
{
    (void)in_sizes; (void)n_in; (void)out_size; (void)ws_size;
    constexpr int Nn = 100000, Nt = 30000, Np = 400000, Ne = 1000000;
    constexpr int H = 64, L = 3, T = 4;

    auto fpt = [&](int i){ return (const float*)d_in[i]; };
    auto ipt = [&](int i){ return (const int*)d_in[i]; };

    const float* in_node = fpt(0);
    const float* in_net  = fpt(1);
    const float* in_pin  = fpt(2);
    const float* in_edge = fpt(3);
    const int* psrc = ipt(4);
    const int* pdst = ipt(5);
    const int* esrc = ipt(6);
    const int* edst = ipt(7);

    float* ws = (float*)d_ws;
    size_t o = 0;
    auto alloc = [&](size_t nel){ float* p = ws + o; o += nel; return p; };
    unsigned short* node_a = (unsigned short*)alloc((size_t)Nn * 32);
    unsigned short* node_b = (unsigned short*)alloc((size_t)Nn * 32);
    unsigned short* aggb   = (unsigned short*)alloc((size_t)Nt * 32);
    unsigned short* hvb    = (unsigned short*)alloc((size_t)Nt * 32);
    unsigned short* hpb    = (unsigned short*)alloc((size_t)Nn * 32);
    unsigned short* ngb    = (unsigned short*)alloc((size_t)Nn * 32);
    float* cff   = alloc((size_t)Nn * 64);                             // fp32 CF accumulator
    float* net_a  = alloc((size_t)Nt * H);
    float* net_b  = alloc((size_t)Nt * H);
    unsigned short* pinb   = (unsigned short*)alloc((size_t)Np * 8);   // bf16 [Np,16]
    unsigned short* pinb_s = (unsigned short*)alloc((size_t)Np * 8);   // slot-permuted
    float* ew3    = alloc((size_t)3 * Ne);
    float* snorm  = alloc((size_t)Nn);
    float* dnorm  = alloc((size_t)Nt);
    int* cnt       = (int*)alloc((size_t)Nn);     // psrc counts (deg), reused by CSR#3
    int* ecnt      = (int*)alloc((size_t)Nn);     // edst counts
    int* row_start = (int*)alloc((size_t)Nn + 1);
    int* nxt       = (int*)alloc((size_t)Nn);
    int* eidx      = (int*)alloc((size_t)Ne);
    int* bsum      = (int*)alloc((size_t)512);
    int* pcnt      = (int*)alloc((size_t)Nt);     // pdst counts (deg), reused by CSR#2
    int* prow      = (int*)alloc((size_t)Nt + 1);
    int* pnxt      = (int*)alloc((size_t)Nt);
    int* peidx     = (int*)alloc((size_t)Np);
    int* pbsum     = (int*)alloc((size_t)256);
    int* srow      = (int*)alloc((size_t)Nn + 1);
    int* seidx     = (int*)alloc((size_t)Np);
    int* pdst_s    = (int*)alloc((size_t)Np);     // pdst in psrc-CSR slot order
    int* snode_s   = (int*)alloc((size_t)Np);     // owning node per slot (non-decreasing)
    int* psrc_s    = (int*)alloc((size_t)Np);     // psrc in pdst-CSR slot order
    float* snorm_s = alloc((size_t)Np);           // snorm in pdst-CSR slot order
    int* esrc_s    = (int*)alloc((size_t)Ne);     // esrc in edst-CSR slot order

    constexpr int NB  = (Nn + 255) / 256;
    constexpr int NB2 = (Nt + 255) / 256;

    // degree counts (shared by norms and pins CSRs)
    hipMemsetAsync(cnt, 0, (size_t)Nn * 4, stream);
    hipMemsetAsync(pcnt, 0, (size_t)Nt * 4, stream);
    deg_kernel<<<(Np + 255) / 256, 256, 0, stream>>>(psrc, pdst, cnt, pcnt, Np);
    norm_out_kernel<<<(Nn + 255) / 256, 256, 0, stream>>>(cnt, snorm, Nn);
    norm_out_kernel<<<(Nt + 255) / 256, 256, 0, stream>>>(pcnt, dnorm, Nt);

    // CSR #1: near keyed by edst (Nn rows)
    hipMemsetAsync(ecnt, 0, (size_t)Nn * 4, stream);
    csr_count_kernel<<<(Ne + 255) / 256, 256, 0, stream>>>(edst, ecnt, Ne);
    scan_block_sum_kernel<<<NB, 256, 0, stream>>>(ecnt, bsum, Nn);
    scan_bsum_kernel<<<1, 512, 0, stream>>>(bsum, NB, row_start + Nn);
    scan_final_kernel<<<NB, 256, 0, stream>>>(ecnt, bsum, row_start, nxt, Nn);
    csr_fill_kernel<<<2048, 256, 0, stream>>>(edst, nxt, eidx, Ne, Nn);
    near_meta_permute_kernel<<<(Ne + 255) / 256, 256, 0, stream>>>(eidx, esrc, esrc_s, Ne);

    // CSR #2: pins keyed by pdst (Nt rows) — counts from deg_kernel (pcnt)
    scan_block_sum_kernel<<<NB2, 256, 0, stream>>>(pcnt, pbsum, Nt);
    scan_bsum_kernel<<<1, 512, 0, stream>>>(pbsum, NB2, prow + Nt);
    scan_final_kernel<<<NB2, 256, 0, stream>>>(pcnt, pbsum, prow, pnxt, Nt);
    csr_fill_kernel<<<1024, 256, 0, stream>>>(pdst, pnxt, peidx, Np, Nt);
    pins_meta_permute_kernel<<<(Np + 255) / 256, 256, 0, stream>>>(peidx, psrc, snorm, psrc_s, snorm_s, Np);

    // CSR #3: pins keyed by psrc (Nn rows) — counts from deg_kernel (cnt)
    scan_block_sum_kernel<<<NB, 256, 0, stream>>>(cnt, bsum, Nn);
    scan_bsum_kernel<<<1, 512, 0, stream>>>(bsum, NB, srow + Nn);
    scan_final_kernel<<<NB, 256, 0, stream>>>(cnt, bsum, srow, nxt, Nn);
    csr_fill_kernel<<<1024, 256, 0, stream>>>(psrc, nxt, seidx, Np, Nn);

    // input encoders
    gemm64_kernel<16, 1, true><<<1024, 256, 0, stream>>>(in_node, fpt(8),  fpt(9),  node_a, Nn);
    gemm64_kernel< 8, 1, false><<<469, 256, 0, stream>>>(in_net,  fpt(10), fpt(11), net_a,  Nt);
    lin_kernel<8, 16, 1, true><<<1024, 256, 0, stream>>>(in_pin, fpt(12), fpt(13), pinb, Np);
    edge_ew_kernel<<<2048, 256, 0, stream>>>(in_edge, fpt(14), fpt(15), fpt(16), fpt(17), ew3, Ne);

    // one-time: permute pin features + pdst + owning-node into psrc-CSR slot order
    pin_permute_kernel<<<(Np + 255) / 256, 256, 0, stream>>>(seidx, pinb, pdst, psrc, pinb_s, pdst_s, snode_s, Np);

    unsigned short* ncur = node_a; unsigned short* nnew = node_b;
    float* tcur = net_a;  float* tnew = net_b;

    for (int i = 0; i < L; i++) {
        // pins GraphConv (node -> net)
        pins_gather_kernel<<<(Nt + 3) / 4, 256, 0, stream>>>(ncur, dnorm, psrc_s, snorm_s, prow, aggb, Nt);
        mfma_gemm_kernel<1, true, false><<<469, 256, 0, stream>>>(aggb, fpt(18) + (size_t)i * 4096, fpt(19) + (size_t)i * 64, tnew, Nt);

        // CFConv (net -> node): hv bf16, fused per-slot HE + gather into fp32 cff
        mfma_gemm_kernel<0, false, true><<<469, 256, 0, stream>>>(tcur, fpt(20) + (size_t)i * 4096, fpt(21) + (size_t)i * 64, hvb, Nt);
        hipMemsetAsync(cff, 0, (size_t)Nn * 64 * 4, stream);
        cf_fused_kernel<<<1024, 256, 0, stream>>>(pinb_s,
                                                  fpt(22) + (size_t)i * 1024, fpt(23) + (size_t)i * 64,
                                                  fpt(24) + (size_t)i * 4096, fpt(25) + (size_t)i * 64,
                                                  hvb, pdst_s, snode_s, cff, Np);

        // SAGE (near)
        mfma_gemm_kernel<2, true, true><<<1024, 256, 0, stream>>>(ncur, fpt(28) + (size_t)i * 4096, fpt(29) + (size_t)i * 64, hpb, Nn);
        sage_gather_kernel<<<(Nn + 3) / 4, 256, 0, stream>>>(hpb, ew3 + (size_t)i * Ne, esrc_s, row_start, eidx, ngb, Nn);

        // combine (cf input fp32)
        mfma_combine_kernel<<<1024, 256, 0, stream>>>(cff, ncur, ngb,
                                                      fpt(26) + (size_t)i * 4096, fpt(27) + (size_t)i * 64,
                                                      fpt(30) + (size_t)i * 4096, fpt(31) + (size_t)i * 4096,
                                                      fpt(32) + (size_t)i * 64,
                                                      nnew, Nn);

        unsigned short* t = ncur; ncur = nnew; nnew = t;
        float* tf = tcur; tcur = tnew; tnew = tf;
    }

    float* out = (float*)d_out;
    node_head_mfma_kernel<<<784, 256, 0, stream>>>(in_node, ncur, fpt(33), fpt(34), fpt(35), fpt(36), fpt(37), fpt(38), out, Nn);
    net_head_mfma_kernel<<<469, 256, 0, stream>>>(in_net, tcur, fpt(39), fpt(40), fpt(41), fpt(42), fpt(43), fpt(44), out + (size_t)Nn * T, Nt);
}

// Round 10
// 958.960 us; speedup vs baseline: 1.0686x; 1.0686x over previous
//
#include <hip/hip_runtime.h>
#include <hip/hip_bf16.h>

#define DEV __device__ __forceinline__

DEV float lrelu_(float x){ return x > 0.f ? x : 0.01f * x; }
DEV float ssp_(float x){ return fmaxf(x, 0.f) + __logf(1.f + __expf(-fabsf(x))) - 0.69314718055994530942f; }
DEV float sigm_(float x){ return 1.f / (1.f + __expf(-x)); }

DEV unsigned short f2bf(float x){
    unsigned int u = __float_as_uint(x);
    unsigned int r = (u + 0x7FFFu + ((u >> 16) & 1u)) >> 16;
    return (unsigned short)r;
}
DEV float bf2f(unsigned short s){ return __uint_as_float((unsigned int)s << 16); }
DEV ushort4 pack4(float4 v){
    ushort4 u; u.x = f2bf(v.x); u.y = f2bf(v.y); u.z = f2bf(v.z); u.w = f2bf(v.w); return u;
}

DEV void fma44(float (&acc)[4][4], const float4 (&xa)[4], const float4 (&wa)[4])
{
    #pragma unroll
    for (int kk = 0; kk < 4; kk++) {
        #pragma unroll
        for (int i = 0; i < 4; i++) {
            float x = ((const float*)&xa[i])[kk];
            #pragma unroll
            for (int j = 0; j < 4; j++)
                acc[i][j] += x * ((const float*)&wa[kk])[j];
        }
    }
}

typedef short s8v __attribute__((ext_vector_type(8)));
typedef float f4v __attribute__((ext_vector_type(4)));

// ====== generic tiled GEMM (VALU, small K): Y[N x 64] = act(X @ W[K x 64] + b) ======
template<int K, int ACT, bool OUTBF>
__global__ __launch_bounds__(256) void gemm64_kernel(const float* __restrict__ X,
                                                     const float* __restrict__ W,
                                                     const float* __restrict__ B,
                                                     void* __restrict__ Yv, int nrows)
{
    constexpr int XS = K + 4;
    constexpr int KQ = K / 4;
    __shared__ float Ws[K * 64];
    __shared__ float bs[64];
    __shared__ float Xs[64 * XS];
    for (int i = threadIdx.x; i < K * 64; i += 256) Ws[i] = W[i];
    if (threadIdx.x < 64) bs[threadIdx.x] = B[threadIdx.x];
    const int tr = threadIdx.x >> 4, tc = threadIdx.x & 15;
    const int r0 = tr * 4, c0 = tc * 4;
    for (int base = blockIdx.x * 64; base < nrows; base += gridDim.x * 64) {
        __syncthreads();
        for (int i = threadIdx.x; i < 64 * KQ; i += 256) {
            int row = i / KQ, kq = (i % KQ) * 4;
            int g = base + row;
            float4 v = make_float4(0.f, 0.f, 0.f, 0.f);
            if (g < nrows) v = *(const float4*)&X[(size_t)g * K + kq];
            *(float4*)&Xs[row * XS + kq] = v;
        }
        __syncthreads();
        float acc[4][4];
        #pragma unroll
        for (int i = 0; i < 4; i++)
            #pragma unroll
            for (int j = 0; j < 4; j++) acc[i][j] = bs[c0 + j];
        #pragma unroll 4
        for (int kq = 0; kq < K; kq += 4) {
            float4 xa[4], wa[4];
            #pragma unroll
            for (int i = 0; i < 4; i++) xa[i] = *(const float4*)&Xs[(r0 + i) * XS + kq];
            #pragma unroll
            for (int j = 0; j < 4; j++) wa[j] = *(const float4*)&Ws[(kq + j) * 64 + c0];
            fma44(acc, xa, wa);
        }
        #pragma unroll
        for (int i = 0; i < 4; i++) {
            int g = base + r0 + i;
            if (g < nrows) {
                float4 o;
                float* op = (float*)&o;
                #pragma unroll
                for (int j = 0; j < 4; j++) {
                    float a = acc[i][j];
                    if (ACT == 1) a = lrelu_(a);
                    else if (ACT == 2) a = fmaxf(a, 0.f);
                    op[j] = a;
                }
                if (OUTBF) *(ushort4*)&((unsigned short*)Yv)[(size_t)g * 64 + c0] = pack4(o);
                else       *(float4*)&((float*)Yv)[(size_t)g * 64 + c0] = o;
            }
        }
    }
}

// ====== MFMA GEMM: Y = act(X @ W64x64 + b); INBF/OUTBF select bf16 storage ======
template<int ACT, bool INBF, bool OUTBF>
__global__ __launch_bounds__(256) void mfma_gemm_kernel(const void* __restrict__ Xv,
                                                        const float* __restrict__ W,
                                                        const float* __restrict__ B,
                                                        void* __restrict__ Yv, int nrows)
{
    __shared__ __align__(16) unsigned short WT[64 * 72];   // [n][k]
    __shared__ __align__(16) unsigned short Axs[64 * 72];  // [row][k]
    __shared__ float bs[64];
    for (int i = threadIdx.x; i < 4096; i += 256) {
        int k = i >> 6, nn = i & 63;
        WT[nn * 72 + k] = f2bf(W[i]);
    }
    if (threadIdx.x < 64) bs[threadIdx.x] = B[threadIdx.x];
    const int lane = threadIdx.x & 63, wv = threadIdx.x >> 6;
    const int l15 = lane & 15, quad = lane >> 4;
    const int arow = 16 * wv + l15;
    const int koff = quad * 8;
    for (int base = blockIdx.x * 64; base < nrows; base += gridDim.x * 64) {
        __syncthreads();
        {
            int row = threadIdx.x >> 2, kq = (threadIdx.x & 3) * 16;
            int g = base + row;
            if (INBF) {
                const unsigned short* Xb = (const unsigned short*)Xv;
                uint4 v0 = make_uint4(0,0,0,0), v1 = v0;
                if (g < nrows) {
                    v0 = *(const uint4*)&Xb[(size_t)g * 64 + kq];
                    v1 = *(const uint4*)&Xb[(size_t)g * 64 + kq + 8];
                }
                *(uint4*)&Axs[row * 72 + kq] = v0;
                *(uint4*)&Axs[row * 72 + kq + 8] = v1;
            } else {
                const float* Xf = (const float*)Xv;
                #pragma unroll
                for (int m = 0; m < 4; m++) {
                    float4 v = make_float4(0,0,0,0);
                    if (g < nrows) v = *(const float4*)&Xf[(size_t)g * 64 + kq + m * 4];
                    *(ushort4*)&Axs[row * 72 + kq + m * 4] = pack4(v);
                }
            }
        }
        __syncthreads();
        f4v acc[4];
        #pragma unroll
        for (int t = 0; t < 4; t++) acc[t] = (f4v){0.f,0.f,0.f,0.f};
        s8v a0 = *(const s8v*)&Axs[arow * 72 + koff];
        s8v a1 = *(const s8v*)&Axs[arow * 72 + 32 + koff];
        #pragma unroll
        for (int t = 0; t < 4; t++) {
            int nn = t * 16 + l15;
            s8v b0 = *(const s8v*)&WT[nn * 72 + koff];
            s8v b1 = *(const s8v*)&WT[nn * 72 + 32 + koff];
            acc[t] = __builtin_amdgcn_mfma_f32_16x16x32_bf16(a0, b0, acc[t], 0, 0, 0);
            acc[t] = __builtin_amdgcn_mfma_f32_16x16x32_bf16(a1, b1, acc[t], 0, 0, 0);
        }
        const int mrow = 16 * wv + quad * 4;
        #pragma unroll
        for (int t = 0; t < 4; t++) {
            int col = t * 16 + l15;
            float b = bs[col];
            #pragma unroll
            for (int r = 0; r < 4; r++) {
                int g = base + mrow + r;
                if (g < nrows) {
                    float a = acc[t][r] + b;
                    if (ACT == 1) a = lrelu_(a);
                    else if (ACT == 2) a = fmaxf(a, 0.f);
                    if (OUTBF) ((unsigned short*)Yv)[(size_t)g * 64 + col] = f2bf(a);
                    else       ((float*)Yv)[(size_t)g * 64 + col] = a;
                }
            }
        }
    }
}

// ====== MFMA triple-GEMM combine (all inputs bf16) ======
__global__ __launch_bounds__(256) void mfma_combine_kernel(const unsigned short* __restrict__ cfb,
                                                           const unsigned short* __restrict__ nfb,
                                                           const unsigned short* __restrict__ ngb,
                                                           const float* __restrict__ Wc, const float* __restrict__ cB,
                                                           const float* __restrict__ sW, const float* __restrict__ nW,
                                                           const float* __restrict__ sB,
                                                           unsigned short* __restrict__ outb, int n)
{
    __shared__ __align__(16) unsigned short WcT[64 * 72], WsT[64 * 72], WnT[64 * 72];
    __shared__ __align__(16) unsigned short Ac[32 * 72], As[32 * 72], An[32 * 72];
    __shared__ float bc[64], bsg[64];
    for (int i = threadIdx.x; i < 4096; i += 256) {
        int k = i >> 6, nn = i & 63;
        WcT[nn * 72 + k] = f2bf(Wc[i]);
        WsT[nn * 72 + k] = f2bf(sW[i]);
        WnT[nn * 72 + k] = f2bf(nW[i]);
    }
    if (threadIdx.x < 64) { bc[threadIdx.x] = cB[threadIdx.x]; bsg[threadIdx.x] = sB[threadIdx.x]; }
    const int lane = threadIdx.x & 63, wv = threadIdx.x >> 6;
    const int l15 = lane & 15, quad = lane >> 4;
    const int arow = (wv & 1) * 16 + l15;
    const int ct0 = (wv >> 1) * 2;
    const int koff = quad * 8;
    for (int base = blockIdx.x * 32; base < n; base += gridDim.x * 32) {
        __syncthreads();
        {
            int row = threadIdx.x >> 3, kq = (threadIdx.x & 7) * 8;
            int g = base + row;
            uint4 vc = make_uint4(0,0,0,0), vf = vc, vg = vc;
            if (g < n) {
                vc = *(const uint4*)&cfb[(size_t)g * 64 + kq];
                vf = *(const uint4*)&nfb[(size_t)g * 64 + kq];
                vg = *(const uint4*)&ngb[(size_t)g * 64 + kq];
            }
            *(uint4*)&Ac[row * 72 + kq] = vc;
            *(uint4*)&As[row * 72 + kq] = vf;
            *(uint4*)&An[row * 72 + kq] = vg;
        }
        __syncthreads();
        f4v accC[2], accS[2];
        #pragma unroll
        for (int t = 0; t < 2; t++) { accC[t] = (f4v){0.f,0.f,0.f,0.f}; accS[t] = (f4v){0.f,0.f,0.f,0.f}; }
        s8v ac0 = *(const s8v*)&Ac[arow * 72 + koff];
        s8v ac1 = *(const s8v*)&Ac[arow * 72 + 32 + koff];
        s8v as0 = *(const s8v*)&As[arow * 72 + koff];
        s8v as1 = *(const s8v*)&As[arow * 72 + 32 + koff];
        s8v an0 = *(const s8v*)&An[arow * 72 + koff];
        s8v an1 = *(const s8v*)&An[arow * 72 + 32 + koff];
        #pragma unroll
        for (int t = 0; t < 2; t++) {
            int nn = (ct0 + t) * 16 + l15;
            s8v wc0 = *(const s8v*)&WcT[nn * 72 + koff];
            s8v wc1 = *(const s8v*)&WcT[nn * 72 + 32 + koff];
            accC[t] = __builtin_amdgcn_mfma_f32_16x16x32_bf16(ac0, wc0, accC[t], 0, 0, 0);
            accC[t] = __builtin_amdgcn_mfma_f32_16x16x32_bf16(ac1, wc1, accC[t], 0, 0, 0);
            s8v ws0 = *(const s8v*)&WsT[nn * 72 + koff];
            s8v ws1 = *(const s8v*)&WsT[nn * 72 + 32 + koff];
            accS[t] = __builtin_amdgcn_mfma_f32_16x16x32_bf16(as0, ws0, accS[t], 0, 0, 0);
            accS[t] = __builtin_amdgcn_mfma_f32_16x16x32_bf16(as1, ws1, accS[t], 0, 0, 0);
            s8v wn0 = *(const s8v*)&WnT[nn * 72 + koff];
            s8v wn1 = *(const s8v*)&WnT[nn * 72 + 32 + koff];
            accS[t] = __builtin_amdgcn_mfma_f32_16x16x32_bf16(an0, wn0, accS[t], 0, 0, 0);
            accS[t] = __builtin_amdgcn_mfma_f32_16x16x32_bf16(an1, wn1, accS[t], 0, 0, 0);
        }
        const int mrow = (wv & 1) * 16 + quad * 4;
        #pragma unroll
        for (int t = 0; t < 2; t++) {
            int col = (ct0 + t) * 16 + l15;
            float bcv = bc[col], bsv = bsg[col];
            #pragma unroll
            for (int r = 0; r < 4; r++) {
                int g = base + mrow + r;
                if (g < n)
                    outb[(size_t)g * 64 + col] = f2bf(lrelu_(fmaxf(ssp_(accC[t][r] + bcv), accS[t][r] + bsv)));
            }
        }
    }
}

// ---------------- small scalar GEMV (pin encoder, C=16) ----------------
template<int K, int C, int ACT, bool OUTBF>
__global__ __launch_bounds__(256) void lin_kernel(const float* __restrict__ X,
                                                  const float* __restrict__ W,
                                                  const float* __restrict__ B,
                                                  void* __restrict__ Yv, int nrows)
{
    constexpr int ROWS = 256 / C;
    __shared__ float Ws[K * C];
    __shared__ float bs[C];
    __shared__ float Xs[ROWS * K];
    for (int i = threadIdx.x; i < K * C; i += 256) Ws[i] = W[i];
    if (threadIdx.x < C) bs[threadIdx.x] = B[threadIdx.x];
    __syncthreads();
    const int r = threadIdx.x / C, c = threadIdx.x % C;
    for (int base = blockIdx.x * ROWS; base < nrows; base += gridDim.x * ROWS) {
        __syncthreads();
        for (int i = threadIdx.x; i < ROWS * K; i += 256) {
            int rr = base + i / K;
            Xs[i] = (rr < nrows) ? X[(size_t)rr * K + i % K] : 0.f;
        }
        __syncthreads();
        int row = base + r;
        if (row < nrows) {
            float acc = bs[c];
            #pragma unroll
            for (int k = 0; k < K; k++) acc += Xs[r * K + k] * Ws[k * C + c];
            if (ACT == 1) acc = lrelu_(acc);
            else if (ACT == 2) acc = fmaxf(acc, 0.f);
            if (OUTBF) ((unsigned short*)Yv)[(size_t)row * C + c] = f2bf(acc);
            else       ((float*)Yv)[(size_t)row * C + c] = acc;
        }
    }
}

// ---------------- degrees: counts into cnt (psrc, Nn) and pcnt (pdst, Nt) ----------------
__global__ __launch_bounds__(256) void deg_kernel(const int* __restrict__ src, const int* __restrict__ dst,
                                                  int* __restrict__ cnt_src, int* __restrict__ cnt_dst, int np)
{
    int p = blockIdx.x * 256 + threadIdx.x;
    if (p < np) { atomicAdd(&cnt_src[src[p]], 1); atomicAdd(&cnt_dst[dst[p]], 1); }
}

// norm_out: out = rsqrt(max(cnt,1)) — non-destructive (counts reused by scans)
__global__ __launch_bounds__(256) void norm_out_kernel(const int* __restrict__ cnt, float* __restrict__ out, int n)
{
    int i = blockIdx.x * 256 + threadIdx.x;
    if (i < n) {
        int v = cnt[i]; if (v < 1) v = 1;
        out[i] = rsqrtf((float)v);
    }
}

// ================= CSR build (generic, keyed by given index array) =================
__global__ __launch_bounds__(256) void csr_count_kernel(const int* __restrict__ key, int* __restrict__ cnt, int ne)
{
    int e = blockIdx.x * 256 + threadIdx.x;
    if (e < ne) atomicAdd(&cnt[key[e]], 1);
}

__global__ __launch_bounds__(256) void scan_block_sum_kernel(const int* __restrict__ cnt, int* __restrict__ bsum, int n)
{
    __shared__ int sh[256];
    int i = blockIdx.x * 256 + threadIdx.x;
    sh[threadIdx.x] = (i < n) ? cnt[i] : 0;
    __syncthreads();
    for (int s = 128; s > 0; s >>= 1) {
        if (threadIdx.x < s) sh[threadIdx.x] += sh[threadIdx.x + s];
        __syncthreads();
    }
    if (threadIdx.x == 0) bsum[blockIdx.x] = sh[0];
}

__global__ __launch_bounds__(512) void scan_bsum_kernel(int* __restrict__ bsum, int nb, int* __restrict__ total_out)
{
    __shared__ int sh[512];
    int i = threadIdx.x;
    int v = (i < nb) ? bsum[i] : 0;
    sh[i] = v;
    __syncthreads();
    for (int s = 1; s < 512; s <<= 1) {
        int add = (i >= s) ? sh[i - s] : 0;
        __syncthreads();
        sh[i] += add;
        __syncthreads();
    }
    if (i < nb) bsum[i] = sh[i] - v;     // exclusive
    if (i == nb - 1) *total_out = sh[i];
}

__global__ __launch_bounds__(256) void scan_final_kernel(const int* __restrict__ cnt, const int* __restrict__ bsum,
                                                         int* __restrict__ row_start, int* __restrict__ nxt, int n)
{
    __shared__ int sh[256];
    int i = blockIdx.x * 256 + threadIdx.x;
    int v = (i < n) ? cnt[i] : 0;
    sh[threadIdx.x] = v;
    __syncthreads();
    for (int s = 1; s < 256; s <<= 1) {
        int add = (threadIdx.x >= s) ? sh[threadIdx.x - s] : 0;
        __syncthreads();
        sh[threadIdx.x] += add;
        __syncthreads();
    }
    if (i < n) {
        int excl = sh[threadIdx.x] - v + bsum[blockIdx.x];
        row_start[i] = excl;
        nxt[i] = excl;
    }
}

// XCD-colored CSR fill (see R2)
__global__ __launch_bounds__(256) void csr_fill_kernel(const int* __restrict__ key, int* __restrict__ nxt,
                                                       int* __restrict__ eidx, int ne, int nrows)
{
    const int color = blockIdx.x & 7;
    const int bid = blockIdx.x >> 3;
    const int nblk = gridDim.x >> 3;
    const int lo = (int)(((long long)nrows * color) >> 3);
    const int hi = (int)(((long long)nrows * (color + 1)) >> 3);
    for (int e = bid * 256 + threadIdx.x; e < ne; e += nblk * 256) {
        int k = key[e];
        if (k >= lo && k < hi) {
            int slot = atomicAdd(&nxt[k], 1);
            eidx[slot] = e;
        }
    }
}

// ---------------- pin feature permutation into psrc-CSR slot order ----------------
__global__ __launch_bounds__(256) void pin_permute_kernel(const int* __restrict__ seidx,
                                                          const unsigned short* __restrict__ pinb,
                                                          const int* __restrict__ pdst,
                                                          unsigned short* __restrict__ pinb_s,
                                                          int* __restrict__ pdst_s, int np)
{
    int slot = blockIdx.x * 256 + threadIdx.x;
    if (slot < np) {
        int p = seidx[slot];
        uint4 a = *(const uint4*)&pinb[(size_t)p * 16];
        uint4 b = *(const uint4*)&pinb[(size_t)p * 16 + 8];
        *(uint4*)&pinb_s[(size_t)slot * 16] = a;
        *(uint4*)&pinb_s[(size_t)slot * 16 + 8] = b;
        pdst_s[slot] = pdst[p];
    }
}

// ---------------- pins-dst CSR metadata permutation: psrc_s/snorm_s in peidx slot order -------
__global__ __launch_bounds__(256) void pins_meta_permute_kernel(const int* __restrict__ peidx,
                                                                const int* __restrict__ psrc,
                                                                const float* __restrict__ snorm,
                                                                int* __restrict__ psrc_s,
                                                                float* __restrict__ snorm_s, int np)
{
    int slot = blockIdx.x * 256 + threadIdx.x;
    if (slot < np) {
        int s = psrc[peidx[slot]];
        psrc_s[slot] = s;
        snorm_s[slot] = snorm[s];
    }
}

// ---------------- near CSR metadata permutation: esrc_s in eidx slot order ----------------
__global__ __launch_bounds__(256) void near_meta_permute_kernel(const int* __restrict__ eidx,
                                                                const int* __restrict__ esrc,
                                                                int* __restrict__ esrc_s, int ne)
{
    int slot = blockIdx.x * 256 + threadIdx.x;
    if (slot < ne) esrc_s[slot] = esrc[eidx[slot]];
}

// ---------------- edge weights for all 3 layers ----------------
__global__ __launch_bounds__(256) void edge_ew_kernel(const float* __restrict__ in_edge,
                                                      const float* __restrict__ elW, const float* __restrict__ elb,
                                                      const float* __restrict__ gW, const float* __restrict__ gb,
                                                      float* __restrict__ ew3, int ne)
{
    __shared__ float W[32], B[8], G[24], Gb[3];
    if (threadIdx.x < 32) W[threadIdx.x] = elW[threadIdx.x];
    if (threadIdx.x < 8)  B[threadIdx.x] = elb[threadIdx.x];
    if (threadIdx.x < 24) G[threadIdx.x] = gW[threadIdx.x];
    if (threadIdx.x < 3)  Gb[threadIdx.x] = gb[threadIdx.x];
    __syncthreads();
    for (int e = blockIdx.x * 256 + threadIdx.x; e < ne; e += gridDim.x * 256) {
        float4 x = *(const float4*)&in_edge[(size_t)e * 4];
        float ef[8];
        #pragma unroll
        for (int j = 0; j < 8; j++)
            ef[j] = lrelu_(B[j] + x.x * W[j] + x.y * W[8 + j] + x.z * W[16 + j] + x.w * W[24 + j]);
        #pragma unroll
        for (int i = 0; i < 3; i++) {
            float a = Gb[i];
            #pragma unroll
            for (int j = 0; j < 8; j++) a += ef[j] * G[i * 8 + j];
            ew3[(size_t)i * ne + e] = sigm_(a);
        }
    }
}

// ---------------- pins GraphConv gather (slot-ordered metadata, unroll-8) -------------
__global__ __launch_bounds__(256) void pins_gather_kernel(const unsigned short* __restrict__ nfb,
                                                          const float* __restrict__ dnorm,
                                                          const int* __restrict__ psrc_s,
                                                          const float* __restrict__ snorm_s,
                                                          const int* __restrict__ prow,
                                                          unsigned short* __restrict__ aggb, int nt)
{
    __shared__ int sS[4][64];
    __shared__ float sN[4][64];
    const int lane = threadIdx.x & 63, wv = threadIdx.x >> 6;
    for (int d = blockIdx.x * 4 + wv; d < nt; d += gridDim.x * 4) {
        int rs = prow[d], re = prow[d + 1];
        float acc = 0.f;
        for (int cbase = rs; cbase < re; cbase += 64) {
            int cnt = re - cbase; if (cnt > 64) cnt = 64;
            if (lane < cnt) {
                sS[wv][lane] = psrc_s[cbase + lane];
                sN[wv][lane] = snorm_s[cbase + lane];
            }
            int k = 0;
            for (; k + 7 < cnt; k += 8) {
                float v[8];
                #pragma unroll
                for (int j = 0; j < 8; j++)
                    v[j] = bf2f(nfb[(size_t)sS[wv][k + j] * 64 + lane]) * sN[wv][k + j];
                acc += ((v[0] + v[1]) + (v[2] + v[3])) + ((v[4] + v[5]) + (v[6] + v[7]));
            }
            for (; k + 3 < cnt; k += 4) {
                float v0 = bf2f(nfb[(size_t)sS[wv][k]   * 64 + lane]) * sN[wv][k];
                float v1 = bf2f(nfb[(size_t)sS[wv][k+1] * 64 + lane]) * sN[wv][k+1];
                float v2 = bf2f(nfb[(size_t)sS[wv][k+2] * 64 + lane]) * sN[wv][k+2];
                float v3 = bf2f(nfb[(size_t)sS[wv][k+3] * 64 + lane]) * sN[wv][k+3];
                acc += (v0 + v1) + (v2 + v3);
            }
            for (; k < cnt; k++)
                acc += bf2f(nfb[(size_t)sS[wv][k] * 64 + lane]) * sN[wv][k];
        }
        aggb[(size_t)d * 64 + lane] = f2bf(acc * dnorm[d]);
    }
}

// ---------------- CFConv per-pin: GEMM1 MFMA(K padded to 32) + GEMM2 MFMA, dense HE write -------
// NOTE: operates on slot-permuted pin features; HE[slot] is in psrc-CSR slot order.
__global__ __launch_bounds__(256) void cf_pin6_kernel(const unsigned short* __restrict__ pinb,
                                                      const float* __restrict__ W1, const float* __restrict__ B1,
                                                      const float* __restrict__ W2, const float* __restrict__ B2,
                                                      unsigned short* __restrict__ HEb, int np)
{
    __shared__ __align__(16) unsigned short W1T[64 * 40];  // B operand [n][k], k 0..31 (16..31 zero)
    __shared__ __align__(16) unsigned short W2T[64 * 72];
    __shared__ __align__(16) unsigned short PFb[64 * 40];  // A rows [p][k 0..31], padded zeros
    __shared__ __align__(16) unsigned short T1s[64 * 72];  // T1 then HE
    __shared__ float bs1[64], bs2[64];
    for (int i = threadIdx.x; i < 64 * 32; i += 256) {
        int n = i & 63, k = i >> 6;
        W1T[n * 40 + k] = (k < 16) ? f2bf(W1[k * 64 + n]) : (unsigned short)0;
    }
    for (int i = threadIdx.x; i < 4096; i += 256) {
        int k = i >> 6, n = i & 63;
        W2T[n * 72 + k] = f2bf(W2[i]);
    }
    if (threadIdx.x < 64) { bs1[threadIdx.x] = B1[threadIdx.x]; bs2[threadIdx.x] = B2[threadIdx.x]; }
    const int lane = threadIdx.x & 63, wv = threadIdx.x >> 6;
    const int l15 = lane & 15, quad = lane >> 4;
    const int arow = 16 * wv + l15;
    const int koff = quad * 8;
    const int mrow = 16 * wv + quad * 4;
    for (int base = blockIdx.x * 64; base < np; base += gridDim.x * 64) {
        __syncthreads();
        {
            int row = threadIdx.x >> 2, q = threadIdx.x & 3;
            int p = base + row;
            uint2 v = make_uint2(0, 0);
            if (p < np) v = *(const uint2*)&pinb[(size_t)p * 16 + q * 4];
            *(uint2*)&PFb[row * 40 + q * 4] = v;
            if (q < 2)
                *(uint4*)&PFb[row * 40 + 16 + q * 8] = make_uint4(0,0,0,0);
        }
        __syncthreads();
        // GEMM1 (MFMA, K=32 zero-padded): T1 = ssp(PF @ W1 + b1)
        {
            f4v acc1[4];
            #pragma unroll
            for (int t = 0; t < 4; t++) acc1[t] = (f4v){0.f,0.f,0.f,0.f};
            s8v a = *(const s8v*)&PFb[arow * 40 + koff];
            #pragma unroll
            for (int t = 0; t < 4; t++) {
                int n = t * 16 + l15;
                s8v b = *(const s8v*)&W1T[n * 40 + koff];
                acc1[t] = __builtin_amdgcn_mfma_f32_16x16x32_bf16(a, b, acc1[t], 0, 0, 0);
            }
            #pragma unroll
            for (int t = 0; t < 4; t++) {
                int col = t * 16 + l15;
                float b = bs1[col];
                #pragma unroll
                for (int r = 0; r < 4; r++)
                    T1s[(mrow + r) * 72 + col] = f2bf(ssp_(acc1[t][r] + b));
            }
        }
        __syncthreads();
        // GEMM2 (MFMA): HE = ssp(T1 @ W2 + b2); overwrites T1s (guarded)
        {
            f4v acc4[4];
            #pragma unroll
            for (int t = 0; t < 4; t++) acc4[t] = (f4v){0.f, 0.f, 0.f, 0.f};
            s8v a0 = *(const s8v*)&T1s[arow * 72 + koff];
            s8v a1 = *(const s8v*)&T1s[arow * 72 + 32 + koff];
            #pragma unroll
            for (int t = 0; t < 4; t++) {
                int n = t * 16 + l15;
                s8v b0 = *(const s8v*)&W2T[n * 72 + koff];
                s8v b1 = *(const s8v*)&W2T[n * 72 + 32 + koff];
                acc4[t] = __builtin_amdgcn_mfma_f32_16x16x32_bf16(a0, b0, acc4[t], 0, 0, 0);
                acc4[t] = __builtin_amdgcn_mfma_f32_16x16x32_bf16(a1, b1, acc4[t], 0, 0, 0);
            }
            __syncthreads();
            #pragma unroll
            for (int t = 0; t < 4; t++) {
                int col = t * 16 + l15;
                float b = bs2[col];
                #pragma unroll
                for (int r = 0; r < 4; r++)
                    T1s[(mrow + r) * 72 + col] = f2bf(ssp_(acc4[t][r] + b));
            }
        }
        __syncthreads();
        // dense coalesced HE write
        {
            int row = threadIdx.x >> 2, kq = (threadIdx.x & 3) * 16;
            int p = base + row;
            if (p < np) {
                *(uint4*)&HEb[(size_t)p * 64 + kq]     = *(const uint4*)&T1s[row * 72 + kq];
                *(uint4*)&HEb[(size_t)p * 64 + kq + 8] = *(const uint4*)&T1s[row * 72 + kq + 8];
            }
        }
    }
}

// ---------------- CF gather over psrc-CSR: h_cf[n] = sum HE[slot] * hv[pdst_s[slot]] ------
// HE rows sequential; pdst_s metadata sequential; only hv (3.8 MB) random.
__global__ __launch_bounds__(256) void cf_gather_kernel(const unsigned short* __restrict__ HEb,
                                                        const unsigned short* __restrict__ hvb,
                                                        const int* __restrict__ pdst_s,
                                                        const int* __restrict__ srow,
                                                        unsigned short* __restrict__ cfb, int nn)
{
    __shared__ int sD[4][64];
    const int lane = threadIdx.x & 63, wv = threadIdx.x >> 6;
    for (int d = blockIdx.x * 4 + wv; d < nn; d += gridDim.x * 4) {
        int rs = srow[d], re = srow[d + 1];
        float acc = 0.f;
        for (int cbase = rs; cbase < re; cbase += 64) {
            int cnt = re - cbase; if (cnt > 64) cnt = 64;
            if (lane < cnt) {
                sD[wv][lane] = pdst_s[cbase + lane];
            }
            int k = 0;
            for (; k + 3 < cnt; k += 4) {
                float he[4], hv[4];
                #pragma unroll
                for (int j = 0; j < 4; j++) {
                    he[j] = bf2f(HEb[(size_t)(cbase + k + j) * 64 + lane]);   // sequential rows
                    hv[j] = bf2f(hvb[(size_t)sD[wv][k + j] * 64 + lane]);
                }
                acc += (he[0] * hv[0] + he[1] * hv[1]) + (he[2] * hv[2] + he[3] * hv[3]);
            }
            for (; k < cnt; k++) {
                acc += bf2f(HEb[(size_t)(cbase + k) * 64 + lane]) * bf2f(hvb[(size_t)sD[wv][k] * 64 + lane]);
            }
        }
        cfb[(size_t)d * 64 + lane] = f2bf(acc);
    }
}

// ---------------- SAGE gather-max (slot-ordered esrc, unroll-8) ----------------
__global__ __launch_bounds__(256) void sage_gather_kernel(const unsigned short* __restrict__ hpb,
                                                          const float* __restrict__ ew,
                                                          const int* __restrict__ esrc_s,
                                                          const int* __restrict__ row_start,
                                                          const int* __restrict__ eidx,
                                                          unsigned short* __restrict__ ngb, int nn)
{
    __shared__ int sS[4][64];
    __shared__ float sWt[4][64];
    const int lane = threadIdx.x & 63, wv = threadIdx.x >> 6;
    for (int d = blockIdx.x * 4 + wv; d < nn; d += gridDim.x * 4) {
        int rs = row_start[d], re = row_start[d + 1];
        float acc = 0.f;
        for (int cbase = rs; cbase < re; cbase += 64) {
            int cnt = re - cbase; if (cnt > 64) cnt = 64;
            if (lane < cnt) {
                sS[wv][lane] = esrc_s[cbase + lane];
                sWt[wv][lane] = ew[eidx[cbase + lane]];
            }
            int k = 0;
            for (; k + 7 < cnt; k += 8) {
                float v[8];
                #pragma unroll
                for (int j = 0; j < 8; j++)
                    v[j] = bf2f(hpb[(size_t)sS[wv][k + j] * 64 + lane]) * sWt[wv][k + j];
                float m0 = fmaxf(fmaxf(v[0], v[1]), fmaxf(v[2], v[3]));
                float m1 = fmaxf(fmaxf(v[4], v[5]), fmaxf(v[6], v[7]));
                acc = fmaxf(acc, fmaxf(m0, m1));
            }
            for (; k + 3 < cnt; k += 4) {
                float v0 = bf2f(hpb[(size_t)sS[wv][k]   * 64 + lane]) * sWt[wv][k];
                float v1 = bf2f(hpb[(size_t)sS[wv][k+1] * 64 + lane]) * sWt[wv][k+1];
                float v2 = bf2f(hpb[(size_t)sS[wv][k+2] * 64 + lane]) * sWt[wv][k+2];
                float v3 = bf2f(hpb[(size_t)sS[wv][k+3] * 64 + lane]) * sWt[wv][k+3];
                acc = fmaxf(acc, fmaxf(fmaxf(v0, v1), fmaxf(v2, v3)));
            }
            for (; k < cnt; k++)
                acc = fmaxf(acc, bf2f(hpb[(size_t)sS[wv][k] * 64 + lane]) * sWt[wv][k]);
        }
        ngb[(size_t)d * 64 + lane] = f2bf(acc);
    }
}

// ---------------- node head (MFMA, 64 rows/tile, 3-stage MLP 80->64->64->4) ----------------
__global__ __launch_bounds__(256) void node_head_mfma_kernel(const float* __restrict__ in_node,
                                                             const unsigned short* __restrict__ nfb,
                                                             const float* __restrict__ W1, const float* __restrict__ B1,
                                                             const float* __restrict__ W2, const float* __restrict__ B2,
                                                             const float* __restrict__ W3, const float* __restrict__ B3,
                                                             float* __restrict__ out, int n)
{
    __shared__ __align__(16) unsigned short W1T[64 * 104];  // [n][k 0..95], k>=80 zero
    __shared__ __align__(16) unsigned short W2T[64 * 72];
    __shared__ __align__(16) unsigned short W3T[16 * 72];   // [c][k], c>=4 zero
    __shared__ __align__(16) unsigned short Xs[64 * 104];   // A rows; reused as H2 [64*72]
    __shared__ __align__(16) unsigned short H1[64 * 72];
    __shared__ float bs1[64], bs2[64], bs3[4];
    for (int i = threadIdx.x; i < 64 * 96; i += 256) {
        int k = i >> 6, nn = i & 63;
        W1T[nn * 104 + k] = (k < 80) ? f2bf(W1[k * 64 + nn]) : (unsigned short)0;
    }
    for (int i = threadIdx.x; i < 4096; i += 256) {
        int k = i >> 6, nn = i & 63;
        W2T[nn * 72 + k] = f2bf(W2[i]);
    }
    for (int i = threadIdx.x; i < 1024; i += 256) {
        int k = i >> 4, c = i & 15;
        W3T[c * 72 + k] = (c < 4) ? f2bf(W3[k * 4 + c]) : (unsigned short)0;
    }
    if (threadIdx.x < 64) { bs1[threadIdx.x] = B1[threadIdx.x]; bs2[threadIdx.x] = B2[threadIdx.x]; }
    if (threadIdx.x < 4) bs3[threadIdx.x] = B3[threadIdx.x];
    const int lane = threadIdx.x & 63, wv = threadIdx.x >> 6;
    const int l15 = lane & 15, quad = lane >> 4;
    const int arow = 16 * wv + l15;
    const int koff = quad * 8;
    const int mrow = 16 * wv + quad * 4;
    unsigned short* H2 = Xs;  // stride 72, fits inside 64*104 region
    for (int base = blockIdx.x * 64; base < n; base += gridDim.x * 64) {
        __syncthreads();
        {
            int row = threadIdx.x >> 2, q = threadIdx.x & 3;
            int g = base + row;
            float4 v = make_float4(0,0,0,0);
            if (g < n) v = *(const float4*)&in_node[(size_t)g * 16 + q * 4];
            *(ushort4*)&Xs[row * 104 + q * 4] = pack4(v);
            uint4 u0 = make_uint4(0,0,0,0), u1 = u0;
            if (g < n) {
                u0 = *(const uint4*)&nfb[(size_t)g * 64 + q * 16];
                u1 = *(const uint4*)&nfb[(size_t)g * 64 + q * 16 + 8];
            }
            *(uint4*)&Xs[row * 104 + 16 + q * 16] = u0;
            *(uint4*)&Xs[row * 104 + 16 + q * 16 + 8] = u1;
            ushort4 z; z.x = 0; z.y = 0; z.z = 0; z.w = 0;
            *(ushort4*)&Xs[row * 104 + 80 + q * 4] = z;  // pad k 80..95
        }
        __syncthreads();
        // GEMM1: H1 = lrelu(X @ W1 + b1), K=96
        {
            f4v acc[4];
            #pragma unroll
            for (int t = 0; t < 4; t++) acc[t] = (f4v){0.f,0.f,0.f,0.f};
            s8v a0 = *(const s8v*)&Xs[arow * 104 + koff];
            s8v a1 = *(const s8v*)&Xs[arow * 104 + 32 + koff];
            s8v a2 = *(const s8v*)&Xs[arow * 104 + 64 + koff];
            #pragma unroll
            for (int t = 0; t < 4; t++) {
                int nn = t * 16 + l15;
                s8v b0 = *(const s8v*)&W1T[nn * 104 + koff];
                s8v b1 = *(const s8v*)&W1T[nn * 104 + 32 + koff];
                s8v b2 = *(const s8v*)&W1T[nn * 104 + 64 + koff];
                acc[t] = __builtin_amdgcn_mfma_f32_16x16x32_bf16(a0, b0, acc[t], 0, 0, 0);
                acc[t] = __builtin_amdgcn_mfma_f32_16x16x32_bf16(a1, b1, acc[t], 0, 0, 0);
                acc[t] = __builtin_amdgcn_mfma_f32_16x16x32_bf16(a2, b2, acc[t], 0, 0, 0);
            }
            #pragma unroll
            for (int t = 0; t < 4; t++) {
                int col = t * 16 + l15;
                float b = bs1[col];
                #pragma unroll
                for (int r = 0; r < 4; r++)
                    H1[(mrow + r) * 72 + col] = f2bf(lrelu_(acc[t][r] + b));
            }
        }
        __syncthreads();
        // GEMM2: H2 = lrelu(H1 @ W2 + b2), K=64; writes into Xs region
        {
            f4v acc[4];
            #pragma unroll
            for (int t = 0; t < 4; t++) acc[t] = (f4v){0.f,0.f,0.f,0.f};
            s8v a0 = *(const s8v*)&H1[arow * 72 + koff];
            s8v a1 = *(const s8v*)&H1[arow * 72 + 32 + koff];
            #pragma unroll
            for (int t = 0; t < 4; t++) {
                int nn = t * 16 + l15;
                s8v b0 = *(const s8v*)&W2T[nn * 72 + koff];
                s8v b1 = *(const s8v*)&W2T[nn * 72 + 32 + koff];
                acc[t] = __builtin_amdgcn_mfma_f32_16x16x32_bf16(a0, b0, acc[t], 0, 0, 0);
                acc[t] = __builtin_amdgcn_mfma_f32_16x16x32_bf16(a1, b1, acc[t], 0, 0, 0);
            }
            __syncthreads();   // all GEMM1 Xs reads done before overwriting
            #pragma unroll
            for (int t = 0; t < 4; t++) {
                int col = t * 16 + l15;
                float b = bs2[col];
                #pragma unroll
                for (int r = 0; r < 4; r++)
                    H2[(mrow + r) * 72 + col] = f2bf(lrelu_(acc[t][r] + b));
            }
        }
        __syncthreads();
        // GEMM3: out = sigm(H2 @ W3 + b3), 4 cols
        {
            f4v acc = (f4v){0.f,0.f,0.f,0.f};
            s8v a0 = *(const s8v*)&H2[arow * 72 + koff];
            s8v a1 = *(const s8v*)&H2[arow * 72 + 32 + koff];
            s8v b0 = *(const s8v*)&W3T[l15 * 72 + koff];
            s8v b1 = *(const s8v*)&W3T[l15 * 72 + 32 + koff];
            acc = __builtin_amdgcn_mfma_f32_16x16x32_bf16(a0, b0, acc, 0, 0, 0);
            acc = __builtin_amdgcn_mfma_f32_16x16x32_bf16(a1, b1, acc, 0, 0, 0);
            if (l15 < 4) {
                float b = bs3[l15];
                #pragma unroll
                for (int r = 0; r < 4; r++) {
                    int g = base + mrow + r;
                    if (g < n) out[(size_t)g * 4 + l15] = sigm_(acc[r] + b);
                }
            }
        }
    }
}

// ---------------- net head (MFMA, 64 rows/tile, 3-stage MLP 72->64->64->1) ----------------
__global__ __launch_bounds__(256) void net_head_mfma_kernel(const float* __restrict__ in_net, const float* __restrict__ tf,
                                                            const float* __restrict__ W1, const float* __restrict__ B1,
                                                            const float* __restrict__ W2, const float* __restrict__ B2,
                                                            const float* __restrict__ W3, const float* __restrict__ B3,
                                                            float* __restrict__ out, int n)
{
    __shared__ __align__(16) unsigned short W1T[64 * 104];  // [n][k 0..95], k>=72 zero
    __shared__ __align__(16) unsigned short W2T[64 * 72];
    __shared__ __align__(16) unsigned short W3T[16 * 72];   // [c][k], c>=1 zero
    __shared__ __align__(16) unsigned short Xs[64 * 104];   // reused as H2
    __shared__ __align__(16) unsigned short H1[64 * 72];
    __shared__ float bs1[64], bs2[64], bs3[1];
    for (int i = threadIdx.x; i < 64 * 96; i += 256) {
        int k = i >> 6, nn = i & 63;
        W1T[nn * 104 + k] = (k < 72) ? f2bf(W1[k * 64 + nn]) : (unsigned short)0;
    }
    for (int i = threadIdx.x; i < 4096; i += 256) {
        int k = i >> 6, nn = i & 63;
        W2T[nn * 72 + k] = f2bf(W2[i]);
    }
    for (int i = threadIdx.x; i < 1024; i += 256) {
        int k = i >> 4, c = i & 15;
        W3T[c * 72 + k] = (c == 0) ? f2bf(W3[k]) : (unsigned short)0;
    }
    if (threadIdx.x < 64) { bs1[threadIdx.x] = B1[threadIdx.x]; bs2[threadIdx.x] = B2[threadIdx.x]; }
    if (threadIdx.x == 0) bs3[0] = B3[0];
    const int lane = threadIdx.x & 63, wv = threadIdx.x >> 6;
    const int l15 = lane & 15, quad = lane >> 4;
    const int arow = 16 * wv + l15;
    const int koff = quad * 8;
    const int mrow = 16 * wv + quad * 4;
    unsigned short* H2 = Xs;
    for (int base = blockIdx.x * 64; base < n; base += gridDim.x * 64) {
        __syncthreads();
        {
            int row = threadIdx.x >> 2, q = threadIdx.x & 3;
            int g = base + row;
            if (q < 2) {
                float4 v = make_float4(0,0,0,0);
                if (g < n) v = *(const float4*)&in_net[(size_t)g * 8 + q * 4];
                *(ushort4*)&Xs[row * 104 + q * 4] = pack4(v);
            }
            #pragma unroll
            for (int m = 0; m < 4; m++) {
                float4 v = make_float4(0,0,0,0);
                if (g < n) v = *(const float4*)&tf[(size_t)g * 64 + q * 16 + m * 4];
                *(ushort4*)&Xs[row * 104 + 8 + q * 16 + m * 4] = pack4(v);
            }
            if (q < 3) {  // pad k 72..95
                ushort4 z; z.x = 0; z.y = 0; z.z = 0; z.w = 0;
                *(ushort4*)&Xs[row * 104 + 72 + q * 8] = z;
                *(ushort4*)&Xs[row * 104 + 72 + q * 8 + 4] = z;
            }
        }
        __syncthreads();
        {
            f4v acc[4];
            #pragma unroll
            for (int t = 0; t < 4; t++) acc[t] = (f4v){0.f,0.f,0.f,0.f};
            s8v a0 = *(const s8v*)&Xs[arow * 104 + koff];
            s8v a1 = *(const s8v*)&Xs[arow * 104 + 32 + koff];
            s8v a2 = *(const s8v*)&Xs[arow * 104 + 64 + koff];
            #pragma unroll
            for (int t = 0; t < 4; t++) {
                int nn = t * 16 + l15;
                s8v b0 = *(const s8v*)&W1T[nn * 104 + koff];
                s8v b1 = *(const s8v*)&W1T[nn * 104 + 32 + koff];
                s8v b2 = *(const s8v*)&W1T[nn * 104 + 64 + koff];
                acc[t] = __builtin_amdgcn_mfma_f32_16x16x32_bf16(a0, b0, acc[t], 0, 0, 0);
                acc[t] = __builtin_amdgcn_mfma_f32_16x16x32_bf16(a1, b1, acc[t], 0, 0, 0);
                acc[t] = __builtin_amdgcn_mfma_f32_16x16x32_bf16(a2, b2, acc[t], 0, 0, 0);
            }
            #pragma unroll
            for (int t = 0; t < 4; t++) {
                int col = t * 16 + l15;
                float b = bs1[col];
                #pragma unroll
                for (int r = 0; r < 4; r++)
                    H1[(mrow + r) * 72 + col] = f2bf(lrelu_(acc[t][r] + b));
            }
        }
        __syncthreads();
        {
            f4v acc[4];
            #pragma unroll
            for (int t = 0; t < 4; t++) acc[t] = (f4v){0.f,0.f,0.f,0.f};
            s8v a0 = *(const s8v*)&H1[arow * 72 + koff];
            s8v a1 = *(const s8v*)&H1[arow * 72 + 32 + koff];
            #pragma unroll
            for (int t = 0; t < 4; t++) {
                int nn = t * 16 + l15;
                s8v b0 = *(const s8v*)&W2T[nn * 72 + koff];
                s8v b1 = *(const s8v*)&W2T[nn * 72 + 32 + koff];
                acc[t] = __builtin_amdgcn_mfma_f32_16x16x32_bf16(a0, b0, acc[t], 0, 0, 0);
                acc[t] = __builtin_amdgcn_mfma_f32_16x16x32_bf16(a1, b1, acc[t], 0, 0, 0);
            }
            __syncthreads();
            #pragma unroll
            for (int t = 0; t < 4; t++) {
                int col = t * 16 + l15;
                float b = bs2[col];
                #pragma unroll
                for (int r = 0; r < 4; r++)
                    H2[(mrow + r) * 72 + col] = f2bf(lrelu_(acc[t][r] + b));
            }
        }
        __syncthreads();
        {
            f4v acc = (f4v){0.f,0.f,0.f,0.f};
            s8v a0 = *(const s8v*)&H2[arow * 72 + koff];
            s8v a1 = *(const s8v*)&H2[arow * 72 + 32 + koff];
            s8v b0 = *(const s8v*)&W3T[l15 * 72 + koff];
            s8v b1 = *(const s8v*)&W3T[l15 * 72 + 32 + koff];
            acc = __builtin_amdgcn_mfma_f32_16x16x32_bf16(a0, b0, acc, 0, 0, 0);
            acc = __builtin_amdgcn_mfma_f32_16x16x32_bf16(a1, b1, acc, 0, 0, 0);
            if (l15 == 0) {
                float b = bs3[0];
                #pragma unroll
                for (int r = 0; r < 4; r++) {
                    int g = base + mrow + r;
                    if (g < n) out[g] = sigm_(acc[r] + b);
                }
            }
        }
    }
}

extern "C" void kernel_launch(void* const* d_in, const int* in_sizes, int n_in,
                              void* d_out, int out_size, void* d_ws, size_t ws_size,
                              hipStream_t stream)
{
    (void)in_sizes; (void)n_in; (void)out_size; (void)ws_size;
    constexpr int Nn = 100000, Nt = 30000, Np = 400000, Ne = 1000000;
    constexpr int H = 64, L = 3, T = 4;

    auto fpt = [&](int i){ return (const float*)d_in[i]; };
    auto ipt = [&](int i){ return (const int*)d_in[i]; };

    const float* in_node = fpt(0);
    const float* in_net  = fpt(1);
    const float* in_pin  = fpt(2);
    const float* in_edge = fpt(3);
    const int* psrc = ipt(4);
    const int* pdst = ipt(5);
    const int* esrc = ipt(6);
    const int* edst = ipt(7);

    float* ws = (float*)d_ws;
    size_t o = 0;
    auto alloc = [&](size_t nel){ float* p = ws + o; o += nel; return p; };
    unsigned short* node_a = (unsigned short*)alloc((size_t)Nn * 32);
    unsigned short* node_b = (unsigned short*)alloc((size_t)Nn * 32);
    unsigned short* aggb   = (unsigned short*)alloc((size_t)Nt * 32);
    unsigned short* hvb    = (unsigned short*)alloc((size_t)Nt * 32);
    unsigned short* hpb    = (unsigned short*)alloc((size_t)Nn * 32);
    unsigned short* ngb    = (unsigned short*)alloc((size_t)Nn * 32);
    unsigned short* HEb    = (unsigned short*)alloc((size_t)Np * 32);
    unsigned short* cfb    = (unsigned short*)alloc((size_t)Nn * 32);
    float* net_a  = alloc((size_t)Nt * H);
    float* net_b  = alloc((size_t)Nt * H);
    unsigned short* pinb   = (unsigned short*)alloc((size_t)Np * 8);   // bf16 [Np,16]
    unsigned short* pinb_s = (unsigned short*)alloc((size_t)Np * 8);   // slot-permuted
    float* ew3    = alloc((size_t)3 * Ne);
    float* snorm  = alloc((size_t)Nn);
    float* dnorm  = alloc((size_t)Nt);
    int* cnt       = (int*)alloc((size_t)Nn);     // psrc counts (deg), reused by CSR#3
    int* ecnt      = (int*)alloc((size_t)Nn);     // edst counts
    int* row_start = (int*)alloc((size_t)Nn + 1);
    int* nxt       = (int*)alloc((size_t)Nn);
    int* eidx      = (int*)alloc((size_t)Ne);
    int* bsum      = (int*)alloc((size_t)512);
    int* pcnt      = (int*)alloc((size_t)Nt);     // pdst counts (deg), reused by CSR#2
    int* prow      = (int*)alloc((size_t)Nt + 1);
    int* pnxt      = (int*)alloc((size_t)Nt);
    int* peidx     = (int*)alloc((size_t)Np);
    int* pbsum     = (int*)alloc((size_t)256);
    int* srow      = (int*)alloc((size_t)Nn + 1);
    int* seidx     = (int*)alloc((size_t)Np);
    int* pdst_s    = (int*)alloc((size_t)Np);     // pdst in psrc-CSR slot order
    int* psrc_s    = (int*)alloc((size_t)Np);     // psrc in pdst-CSR slot order
    float* snorm_s = alloc((size_t)Np);           // snorm in pdst-CSR slot order
    int* esrc_s    = (int*)alloc((size_t)Ne);     // esrc in edst-CSR slot order

    constexpr int NB  = (Nn + 255) / 256;
    constexpr int NB2 = (Nt + 255) / 256;

    // degree counts (shared by norms and pins CSRs)
    hipMemsetAsync(cnt, 0, (size_t)Nn * 4, stream);
    hipMemsetAsync(pcnt, 0, (size_t)Nt * 4, stream);
    deg_kernel<<<(Np + 255) / 256, 256, 0, stream>>>(psrc, pdst, cnt, pcnt, Np);
    norm_out_kernel<<<(Nn + 255) / 256, 256, 0, stream>>>(cnt, snorm, Nn);
    norm_out_kernel<<<(Nt + 255) / 256, 256, 0, stream>>>(pcnt, dnorm, Nt);

    // CSR #1: near keyed by edst (Nn rows)
    hipMemsetAsync(ecnt, 0, (size_t)Nn * 4, stream);
    csr_count_kernel<<<(Ne + 255) / 256, 256, 0, stream>>>(edst, ecnt, Ne);
    scan_block_sum_kernel<<<NB, 256, 0, stream>>>(ecnt, bsum, Nn);
    scan_bsum_kernel<<<1, 512, 0, stream>>>(bsum, NB, row_start + Nn);
    scan_final_kernel<<<NB, 256, 0, stream>>>(ecnt, bsum, row_start, nxt, Nn);
    csr_fill_kernel<<<2048, 256, 0, stream>>>(edst, nxt, eidx, Ne, Nn);
    near_meta_permute_kernel<<<(Ne + 255) / 256, 256, 0, stream>>>(eidx, esrc, esrc_s, Ne);

    // CSR #2: pins keyed by pdst (Nt rows) — counts from deg_kernel (pcnt)
    scan_block_sum_kernel<<<NB2, 256, 0, stream>>>(pcnt, pbsum, Nt);
    scan_bsum_kernel<<<1, 512, 0, stream>>>(pbsum, NB2, prow + Nt);
    scan_final_kernel<<<NB2, 256, 0, stream>>>(pcnt, pbsum, prow, pnxt, Nt);
    csr_fill_kernel<<<1024, 256, 0, stream>>>(pdst, pnxt, peidx, Np, Nt);
    pins_meta_permute_kernel<<<(Np + 255) / 256, 256, 0, stream>>>(peidx, psrc, snorm, psrc_s, snorm_s, Np);

    // CSR #3: pins keyed by psrc (Nn rows) — counts from deg_kernel (cnt)
    scan_block_sum_kernel<<<NB, 256, 0, stream>>>(cnt, bsum, Nn);
    scan_bsum_kernel<<<1, 512, 0, stream>>>(bsum, NB, srow + Nn);
    scan_final_kernel<<<NB, 256, 0, stream>>>(cnt, bsum, srow, nxt, Nn);
    csr_fill_kernel<<<1024, 256, 0, stream>>>(psrc, nxt, seidx, Np, Nn);

    // input encoders
    gemm64_kernel<16, 1, true><<<1024, 256, 0, stream>>>(in_node, fpt(8),  fpt(9),  node_a, Nn);
    gemm64_kernel< 8, 1, false><<<469, 256, 0, stream>>>(in_net,  fpt(10), fpt(11), net_a,  Nt);
    lin_kernel<8, 16, 1, true><<<1024, 256, 0, stream>>>(in_pin, fpt(12), fpt(13), pinb, Np);
    edge_ew_kernel<<<2048, 256, 0, stream>>>(in_edge, fpt(14), fpt(15), fpt(16), fpt(17), ew3, Ne);

    // one-time: permute pin features + pdst into psrc-CSR slot order
    pin_permute_kernel<<<(Np + 255) / 256, 256, 0, stream>>>(seidx, pinb, pdst, pinb_s, pdst_s, Np);

    unsigned short* ncur = node_a; unsigned short* nnew = node_b;
    float* tcur = net_a;  float* tnew = net_b;

    for (int i = 0; i < L; i++) {
        // pins GraphConv (node -> net)
        pins_gather_kernel<<<(Nt + 3) / 4, 256, 0, stream>>>(ncur, dnorm, psrc_s, snorm_s, prow, aggb, Nt);
        mfma_gemm_kernel<1, true, false><<<469, 256, 0, stream>>>(aggb, fpt(18) + (size_t)i * 4096, fpt(19) + (size_t)i * 64, tnew, Nt);

        // CFConv (net -> node): hv bf16, per-slot HE (sequential), then psrc-CSR gather
        mfma_gemm_kernel<0, false, true><<<469, 256, 0, stream>>>(tcur, fpt(20) + (size_t)i * 4096, fpt(21) + (size_t)i * 64, hvb, Nt);
        cf_pin6_kernel<<<2048, 256, 0, stream>>>(pinb_s,
                                                 fpt(22) + (size_t)i * 1024, fpt(23) + (size_t)i * 64,
                                                 fpt(24) + (size_t)i * 4096, fpt(25) + (size_t)i * 64,
                                                 HEb, Np);
        cf_gather_kernel<<<(Nn + 3) / 4, 256, 0, stream>>>(HEb, hvb, pdst_s, srow, cfb, Nn);

        // SAGE (near)
        mfma_gemm_kernel<2, true, true><<<1024, 256, 0, stream>>>(ncur, fpt(28) + (size_t)i * 4096, fpt(29) + (size_t)i * 64, hpb, Nn);
        sage_gather_kernel<<<(Nn + 3) / 4, 256, 0, stream>>>(hpb, ew3 + (size_t)i * Ne, esrc_s, row_start, eidx, ngb, Nn);

        // combine
        mfma_combine_kernel<<<1024, 256, 0, stream>>>(cfb, ncur, ngb,
                                                      fpt(26) + (size_t)i * 4096, fpt(27) + (size_t)i * 64,
                                                      fpt(30) + (size_t)i * 4096, fpt(31) + (size_t)i * 4096,
                                                      fpt(32) + (size_t)i * 64,
                                                      nnew, Nn);

        unsigned short* t = ncur; ncur = nnew; nnew = t;
        float* tf = tcur; tcur = tnew; tnew = tf;
    }

    float* out = (float*)d_out;
    node_head_mfma_kernel<<<784, 256, 0, stream>>>(in_node, ncur, fpt(33), fpt(34), fpt(35), fpt(36), fpt(37), fpt(38), out, Nn);
    net_head_mfma_kernel<<<469, 256, 0, stream>>>(in_net, tcur, fpt(39), fpt(40), fpt(41), fpt(42), fpt(43), fpt(44), out + (size_t)Nn * T, Nt);
}